// Round 5
// baseline (7818.538 us; speedup 1.0000x reference)
//
#include <hip/hip_runtime.h>
#include <hip/hip_bf16.h>

#define DI __device__ __forceinline__

typedef __bf16 bf16x8 __attribute__((ext_vector_type(8)));
typedef __bf16 bf16x4 __attribute__((ext_vector_type(4)));
typedef __bf16 bf16x2 __attribute__((ext_vector_type(2)));
typedef float  f32x4  __attribute__((ext_vector_type(4)));
typedef unsigned long long ull;

static constexpr int Bc = 64, Tc = 256, Ic = 128, Hc = 512, Oc = 64;
static constexpr int TBc = Tc * Bc;                 // 16384
static constexpr size_t THW = (size_t)TBc * Hc;     // 8388608 elems

// ---------- d_out offsets (floats) ----------
static constexpr size_t O_OUT = 0;
static constexpr size_t O_HT  = 4096;
static constexpr size_t O_DW0 = 36864;
static constexpr size_t O_DV0 = 823296;
static constexpr size_t O_DB0 = 1019904;
static constexpr size_t O_ERR = 1021440;

// ---------- ws offsets (bytes) ----------
static constexpr size_t W_SLOT = 1024;     // 9 f32
static constexpr size_t W_DB   = 2048;     // db_raw [3][512] f32 -> ends 8192
static constexpr size_t W_ERRW = 16384;    // error [64][64] f32
static constexpr size_t W_PROJ = 32768;    // proj [6][64][512] f32 -> ends 819200
// Exchange region: [4 group][2 buf][3 comp][8192] u32 = 786432 B, spans
// 819200..1605632. ALIASES W1B (bf16 W1) + old hx/hrx: k0_cast therefore runs
// AFTER k2 (k4 is the only W1B consumer).
static constexpr size_t W_EXCH = 819200;
static constexpr size_t W_W1B  = 819200;   // W1 bf16 [512][512] (post-k2)
static constexpr size_t W_XT   = 1605632;  // x^T bf16 [128][TB] -> ends 5799936
static constexpr size_t W_HIST = 5799936;  // r,z,ht,h bf16 [TB][512] each -> ends 72908800
static constexpr size_t W_PB   = 72908800; // xV fp32 (100.6MB) / later P + HpT + RsHpT
static constexpr size_t W_NEED = W_PB + 100663296;   // 173572096

// =========================== helpers ===========================

DI ull ld64_agent(const void* p) {
  return __hip_atomic_load((ull*)p, __ATOMIC_RELAXED, __HIP_MEMORY_SCOPE_AGENT);
}
DI void stu32_agent(unsigned int* p, unsigned int v) {
  __hip_atomic_store(p, v, __ATOMIC_RELAXED, __HIP_MEMORY_SCOPE_AGENT);
}
DI unsigned short bfbits(__bf16 x) {
  union { __bf16 b; unsigned short u; } c; c.b = x; return c.u;
}
// self-validating exchange word: {bf16 payload | epoch16}
DI unsigned int pack_xw(__bf16 x, int ep) {
  return ((unsigned int)bfbits(x) << 16) | (unsigned int)(ep & 0xffff);
}

// hiddens[t-1] with python-negative-index quirk; k = t*64+b
DI float hprev_at(const __bf16* __restrict__ h_h, int k, int col) {
  int t = k >> 6;
  if (t == 1) return 0.f;
  int row = (t == 0) ? (16320 + (k & 63)) : (k - 128);
  return (float)h_h[(size_t)row * 512 + col];
}

// =========================== tiny kernels ===========================

__global__ void kzero(float* __restrict__ p, int n) {
  int i = blockIdx.x * 256 + threadIdx.x;
  if (i < n) p[i] = 0.f;
}
__global__ void ksent(float* p, float v) { p[0] = v; }
__global__ void k0_cast(const float* __restrict__ s, __bf16* __restrict__ d, int n) {
  int i = blockIdx.x * 256 + threadIdx.x;
  if (i < n) d[i] = (__bf16)s[i];
}

// =========================== K1: xV = x@V^T + bias (fp32) ===========================
__global__ __launch_bounds__(256)
void k1_xv(const float* __restrict__ x, const float* __restrict__ V1w,
           const float* __restrict__ V2w, const float* __restrict__ V3w,
           const float* __restrict__ V1b, const float* __restrict__ W2b,
           const float* __restrict__ W3b,
           float* __restrict__ xv1f, float* __restrict__ xv2f, float* __restrict__ xv3f)
{
  const int cb = blockIdx.x, t = blockIdx.y;
  const int g = cb >> 3, jblk = cb & 7;
  const float* Vg   = (g == 0) ? V1w : (g == 1) ? V2w : V3w;
  const float* bias = (g == 0) ? V1b : (g == 1) ? W2b : W3b;
  float* of = (g == 0) ? xv1f : (g == 1) ? xv2f : xv3f;
  __shared__ float As[64 * 69];
  __shared__ float Bs[64 * 69];
  const int tid = threadIdx.x;
  float acc[4][4] = {};
  const int m0 = (tid & 15) * 4, j0 = (tid >> 4) * 4;
  for (int kc = 0; kc < 2; ++kc) {
    __syncthreads();
    #pragma unroll
    for (int e = 0; e < 4; ++e) {
      int idx = tid + e * 256;            // 0..1023
      int row = idx >> 4, c4 = (idx & 15) * 4;
      float4 v = *reinterpret_cast<const float4*>(&x[((size_t)row * 256 + t) * 128 + kc * 64 + c4]);
      As[row * 69 + c4 + 0] = v.x; As[row * 69 + c4 + 1] = v.y;
      As[row * 69 + c4 + 2] = v.z; As[row * 69 + c4 + 3] = v.w;
      float4 w = *reinterpret_cast<const float4*>(&Vg[(size_t)(jblk * 64 + row) * 128 + kc * 64 + c4]);
      Bs[row * 69 + c4 + 0] = w.x; Bs[row * 69 + c4 + 1] = w.y;
      Bs[row * 69 + c4 + 2] = w.z; Bs[row * 69 + c4 + 3] = w.w;
    }
    __syncthreads();
    for (int i = 0; i < 64; ++i) {
      float a[4], b[4];
      #pragma unroll
      for (int u = 0; u < 4; ++u) a[u] = As[(m0 + u) * 69 + i];
      #pragma unroll
      for (int u = 0; u < 4; ++u) b[u] = Bs[(j0 + u) * 69 + i];
      #pragma unroll
      for (int mi = 0; mi < 4; ++mi)
        #pragma unroll
        for (int ji = 0; ji < 4; ++ji) acc[mi][ji] += a[mi] * b[ji];
    }
  }
  #pragma unroll
  for (int ji = 0; ji < 4; ++ji) {
    int jg = jblk * 64 + j0 + ji;
    float bv = bias[jg];
    #pragma unroll
    for (int mi = 0; mi < 4; ++mi) {
      int b = m0 + mi;
      of[((size_t)t * 64 + b) * 512 + jg] = acc[mi][ji] + bv;
    }
  }
}

// =========================== E0: X^T bf16 [128][TB] ===========================
__global__ void e0_xt(const float* __restrict__ x, __bf16* __restrict__ XT)
{
  const int t = blockIdx.x;
  __shared__ __bf16 xs[64 * 132];
  const int tid = threadIdx.x;
  #pragma unroll
  for (int e = 0; e < 8; ++e) {
    int idx = tid + e * 256;              // 0..2047
    int b = idx >> 5, c4 = (idx & 31) * 4;
    float4 v = *reinterpret_cast<const float4*>(&x[((size_t)b * 256 + t) * 128 + c4]);
    xs[b * 132 + c4 + 0] = (__bf16)v.x; xs[b * 132 + c4 + 1] = (__bf16)v.y;
    xs[b * 132 + c4 + 2] = (__bf16)v.z; xs[b * 132 + c4 + 3] = (__bf16)v.w;
  }
  __syncthreads();
  #pragma unroll
  for (int e = 0; e < 8; ++e) {
    int idx = tid + e * 256;
    int i = idx >> 4, b4 = (idx & 15) * 4;
    __bf16* d = &XT[(size_t)i * TBc + t * 64 + b4];
    d[0] = xs[(b4 + 0) * 132 + i];
    d[1] = xs[(b4 + 1) * 132 + i];
    d[2] = xs[(b4 + 2) * 132 + i];
    d[3] = xs[(b4 + 3) * 132 + i];
  }
}

// =========================== K2: persistent GRU recurrence, fp32-faithful =========
// 64 wgs = 4 batch-groups(16 rows) x 16 col-wgs(32 cols). 4 waves/wg =
// 2 col-tiles x 2 k-halves. Both operands split 3-way bf16 (Ootomo 6-term
// MFMA). NO flags, NO group barrier: the h/hr exchange is SELF-VALIDATING --
// owner pre-splits fp32 h into 3 bf16 components and stores each as
// u32 {bf16|epoch16} (agent scope, MALL). Consumers poll the data words
// directly until every word carries the current epoch. This removes the
// store-drain + flag-store + flag-poll round-trips from the critical path
// (stores drain async while consumers poll) and moves the 3-way-split VALU
// to the owner (4 values) instead of consumers (64 values each).
// Flow control: a wg writes epoch e+1 into buffer X only after staging the
// OTHER buffer at epoch e, which requires every wg to have fully consumed
// X at epoch e -- no overwrite-while-reading. pbuf lane stride 9 (conflict-free).
__global__ __launch_bounds__(256, 1)
void k2_recur(const float* __restrict__ W1w, const float* __restrict__ W2w,
              const float* __restrict__ W3w,
              const float* __restrict__ xv1, const float* __restrict__ xv2,
              const float* __restrict__ xv3,
              __bf16* __restrict__ r_h, __bf16* __restrict__ z_h,
              __bf16* __restrict__ ht_h, __bf16* __restrict__ h_h,
              unsigned int* __restrict__ exch, float* __restrict__ dout)
{
  const int g  = blockIdx.x >> 4;      // batch group 0..3
  const int cw = blockIdx.x & 15;      // col-wg 0..15
  const int tid = threadIdx.x, lane = tid & 63, wv = tid >> 6;
  const int kh = wv & 1;               // k-half
  const int ct = wv >> 1;              // col-tile
  const int q  = lane >> 4;
  const int colc = cw * 32 + ct * 16 + (lane & 15);
  const bool owner = (kh == 0);

  __shared__ __align__(16) __bf16 c0[8192];   // h comp0 frags [16kk][64lane][8]
  __shared__ __align__(16) __bf16 c1[8192];
  __shared__ __align__(16) __bf16 c2[8192];
  __shared__ float pbuf[128 * 9];             // cross-wave partials, 9-stride

  // weight fragments, 3-way split: lane n=colc, k = (kh*8+kk2)*32 + q*8 + j
  bf16x8 w1c[3][8], w2c[3][8], w3c[3][8];
  #pragma unroll
  for (int kk2 = 0; kk2 < 8; ++kk2) {
    const int kb = (kh * 8 + kk2) * 32 + q * 8;
    #pragma unroll
    for (int j = 0; j < 8; ++j) {
      float w = W1w[(size_t)colc * 512 + kb + j];
      __bf16 a = (__bf16)w; float r1 = w - (float)a;
      __bf16 b = (__bf16)r1;
      w1c[0][kk2][j] = a; w1c[1][kk2][j] = b; w1c[2][kk2][j] = (__bf16)(r1 - (float)b);
      w = W2w[(size_t)colc * 512 + kb + j];
      a = (__bf16)w; r1 = w - (float)a; b = (__bf16)r1;
      w2c[0][kk2][j] = a; w2c[1][kk2][j] = b; w2c[2][kk2][j] = (__bf16)(r1 - (float)b);
      w = W3w[(size_t)colc * 512 + kb + j];
      a = (__bf16)w; r1 = w - (float)a; b = (__bf16)r1;
      w3c[0][kk2][j] = a; w3c[1][kk2][j] = b; w3c[2][kk2][j] = (__bf16)(r1 - (float)b);
    }
  }
  for (int i = tid; i < 8192; i += 256) {
    c0[i] = (__bf16)0.f; c1[i] = (__bf16)0.f; c2[i] = (__bf16)0.f;
  }
  __syncthreads();

  float hreg[4] = {0.f, 0.f, 0.f, 0.f};
  // exchange: [group][2 buf][3 comp][8192] u32
  unsigned int* hrx_g = exch + (size_t)g * 49152;          // buf0
  unsigned int* hx_g  = hrx_g + 24576;                     // buf1
  // frag index for state element (m=q*4+i, c=colc)
  const int fragbase = (colc >> 5) * 512 + (((colc >> 3) & 3) * 16 + q * 4) * 8 + (colc & 7);
  const int pb = (ct * 64 + lane) * 9;

  bool dead = false;

  // poll-and-stage: retry whole 3-comp read until every word's epoch == ep,
  // then LDS holds the staged fragments (last pass rewrote everything fresh).
  auto stage_poll = [&](const unsigned int* __restrict__ base, int ep) {
    int spins = 0;
    for (;;) {
      bool ok = true;
      #pragma unroll
      for (int cc = 0; cc < 3; ++cc) {
        const ull* src = reinterpret_cast<const ull*>(base + cc * 8192);
        __bf16* dst = (cc == 0) ? c0 : (cc == 1) ? c1 : c2;
        ull u[16];
        #pragma unroll
        for (int j = 0; j < 16; ++j) u[j] = ld64_agent(src + tid + j * 256);
        #pragma unroll
        for (int j = 0; j < 16; ++j) {
          ok = ok && ((int)(u[j] & 0xffffu) == ep)
                  && ((int)((u[j] >> 32) & 0xffffu) == ep);
          int o = tid + j * 256;
          unsigned int w = (unsigned int)((u[j] >> 16) & 0xffffu)
                         | ((unsigned int)(u[j] >> 48) << 16);
          *reinterpret_cast<unsigned int*>(&dst[2 * o]) = w;
        }
      }
      if (dead || __all(ok)) break;
      __builtin_amdgcn_s_sleep(1);
      if (++spins > 1000000) { dead = true; break; }   // never hang the bench
    }
  };

  #pragma unroll 1
  for (int t = 0; t < Tc; ++t) {
    const int ep = t + 1;
    const size_t rowb = ((size_t)t * 64 + g * 16 + q * 4) * 512 + colc;
    float xv1v[4], xv2v[4], xv3v[4];
    if (owner) {
      #pragma unroll
      for (int i = 0; i < 4; ++i) {
        size_t o = rowb + (size_t)i * 512;
        xv1v[i] = xv1[o]; xv2v[i] = xv2[o]; xv3v[i] = xv3[o];
      }
    }
    // ---- phase 1: z, r gates ----
    f32x4 a2 = {0.f,0.f,0.f,0.f}, a3 = {0.f,0.f,0.f,0.f};
    #pragma unroll
    for (int kk2 = 0; kk2 < 8; ++kk2) {
      const int idx = (kh * 8 + kk2) * 512 + lane * 8;
      bf16x8 h0 = *reinterpret_cast<const bf16x8*>(&c0[idx]);
      bf16x8 h1 = *reinterpret_cast<const bf16x8*>(&c1[idx]);
      bf16x8 h2 = *reinterpret_cast<const bf16x8*>(&c2[idx]);
      a2 = __builtin_amdgcn_mfma_f32_16x16x32_bf16(h0, w2c[0][kk2], a2, 0, 0, 0);
      a2 = __builtin_amdgcn_mfma_f32_16x16x32_bf16(h1, w2c[0][kk2], a2, 0, 0, 0);
      a2 = __builtin_amdgcn_mfma_f32_16x16x32_bf16(h0, w2c[1][kk2], a2, 0, 0, 0);
      a2 = __builtin_amdgcn_mfma_f32_16x16x32_bf16(h2, w2c[0][kk2], a2, 0, 0, 0);
      a2 = __builtin_amdgcn_mfma_f32_16x16x32_bf16(h1, w2c[1][kk2], a2, 0, 0, 0);
      a2 = __builtin_amdgcn_mfma_f32_16x16x32_bf16(h0, w2c[2][kk2], a2, 0, 0, 0);
      a3 = __builtin_amdgcn_mfma_f32_16x16x32_bf16(h0, w3c[0][kk2], a3, 0, 0, 0);
      a3 = __builtin_amdgcn_mfma_f32_16x16x32_bf16(h1, w3c[0][kk2], a3, 0, 0, 0);
      a3 = __builtin_amdgcn_mfma_f32_16x16x32_bf16(h0, w3c[1][kk2], a3, 0, 0, 0);
      a3 = __builtin_amdgcn_mfma_f32_16x16x32_bf16(h2, w3c[0][kk2], a3, 0, 0, 0);
      a3 = __builtin_amdgcn_mfma_f32_16x16x32_bf16(h1, w3c[1][kk2], a3, 0, 0, 0);
      a3 = __builtin_amdgcn_mfma_f32_16x16x32_bf16(h0, w3c[2][kk2], a3, 0, 0, 0);
    }
    if (!owner) {
      #pragma unroll
      for (int i = 0; i < 4; ++i) { pbuf[pb + i] = a2[i]; pbuf[pb + 4 + i] = a3[i]; }
    }
    __syncthreads();
    float zz[4], rr4[4];
    if (owner) {
      // exchange stores first (consumers poll on them), history stores after
      #pragma unroll
      for (int i = 0; i < 4; ++i) {
        float s2 = a2[i] + pbuf[pb + i]     + xv2v[i];
        float s3 = a3[i] + pbuf[pb + 4 + i] + xv3v[i];
        zz[i]  = 1.f / (1.f + expf(-s2));
        rr4[i] = 1.f / (1.f + expf(-s3));
        float hv = hreg[i] * rr4[i];
        __bf16 a = (__bf16)hv; float r1 = hv - (float)a;
        __bf16 b = (__bf16)r1; __bf16 cres = (__bf16)(r1 - (float)b);
        int w = fragbase + i * 8;
        stu32_agent(&hrx_g[w],          pack_xw(a, ep));
        stu32_agent(&hrx_g[8192 + w],   pack_xw(b, ep));
        stu32_agent(&hrx_g[16384 + w],  pack_xw(cres, ep));
      }
      #pragma unroll
      for (int i = 0; i < 4; ++i) {
        z_h[rowb + (size_t)i * 512] = (__bf16)zz[i];
        r_h[rowb + (size_t)i * 512] = (__bf16)rr4[i];
      }
    }
    stage_poll(hrx_g, ep);
    __syncthreads();
    // ---- phase 2: candidate + update ----
    f32x4 a1 = {0.f,0.f,0.f,0.f};
    #pragma unroll
    for (int kk2 = 0; kk2 < 8; ++kk2) {
      const int idx = (kh * 8 + kk2) * 512 + lane * 8;
      bf16x8 h0 = *reinterpret_cast<const bf16x8*>(&c0[idx]);
      bf16x8 h1 = *reinterpret_cast<const bf16x8*>(&c1[idx]);
      bf16x8 h2 = *reinterpret_cast<const bf16x8*>(&c2[idx]);
      a1 = __builtin_amdgcn_mfma_f32_16x16x32_bf16(h0, w1c[0][kk2], a1, 0, 0, 0);
      a1 = __builtin_amdgcn_mfma_f32_16x16x32_bf16(h1, w1c[0][kk2], a1, 0, 0, 0);
      a1 = __builtin_amdgcn_mfma_f32_16x16x32_bf16(h0, w1c[1][kk2], a1, 0, 0, 0);
      a1 = __builtin_amdgcn_mfma_f32_16x16x32_bf16(h2, w1c[0][kk2], a1, 0, 0, 0);
      a1 = __builtin_amdgcn_mfma_f32_16x16x32_bf16(h1, w1c[1][kk2], a1, 0, 0, 0);
      a1 = __builtin_amdgcn_mfma_f32_16x16x32_bf16(h0, w1c[2][kk2], a1, 0, 0, 0);
    }
    if (!owner) {
      #pragma unroll
      for (int i = 0; i < 4; ++i) pbuf[pb + i] = a1[i];
    }
    __syncthreads();
    if (owner) {
      float htv[4];
      #pragma unroll
      for (int i = 0; i < 4; ++i) {
        float pre = a1[i] + pbuf[pb + i] + xv1v[i];
        float ht = tanhf(pre);
        float hn = zz[i] * (hreg[i] - ht) + ht;
        htv[i] = ht;
        hreg[i] = hn;
        __bf16 a = (__bf16)hn; float r1 = hn - (float)a;
        __bf16 b = (__bf16)r1; __bf16 cres = (__bf16)(r1 - (float)b);
        int w = fragbase + i * 8;
        stu32_agent(&hx_g[w],          pack_xw(a, ep));
        stu32_agent(&hx_g[8192 + w],   pack_xw(b, ep));
        stu32_agent(&hx_g[16384 + w],  pack_xw(cres, ep));
      }
      #pragma unroll
      for (int i = 0; i < 4; ++i) {
        ht_h[rowb + (size_t)i * 512] = (__bf16)htv[i];
        h_h[rowb + (size_t)i * 512]  = (__bf16)hreg[i];
      }
    }
    if (t + 1 < Tc) {
      stage_poll(hx_g, ep);
    }
    __syncthreads();
  }
  if (owner) {
    #pragma unroll
    for (int i = 0; i < 4; ++i) {
      int b = g * 16 + q * 4 + i;
      dout[O_HT + (size_t)b * 512 + colc] = hreg[i];
    }
  }
}

// =========================== K3a: logits/softmax/error ===========================
__global__ void k3a_soft(const float* __restrict__ Woutw, const float* __restrict__ Woutb,
                         const int* __restrict__ y, float* __restrict__ dout,
                         float* __restrict__ errw)
{
  const int b = blockIdx.x, o = threadIdx.x;
  const float* hrow = dout + O_HT + (size_t)b * 512;
  float sv = Woutb[o];
  for (int k = 0; k < 512; ++k) sv += hrow[k] * Woutw[(size_t)o * 512 + k];
  float mx = sv;
  for (int off = 32; off; off >>= 1) mx = fmaxf(mx, __shfl_xor(mx, off, 64));
  float e = expf(sv - mx);
  float sum = e;
  for (int off = 32; off; off >>= 1) sum += __shfl_xor(sum, off, 64);
  float outp = e / sum;
  float errv = outp - ((y[b] == o) ? 1.f : 0.f);
  dout[O_OUT + b * 64 + o] = outp;
  dout[O_ERR + b * 64 + o] = errv;
  errw[b * 64 + o] = errv;
}

// =========================== K3b: 6 DFA projections ===========================
__global__ __launch_bounds__(256)
void k3b_proj(const float* __restrict__ err,
              const float* b0, const float* b1, const float* b2,
              const float* b3, const float* b4, const float* b5,
              float* __restrict__ proj)
{
  const int p = blockIdx.y;
  const int hb = blockIdx.x * 64;
  const float* BX = (p==0)?b0:(p==1)?b1:(p==2)?b2:(p==3)?b3:(p==4)?b4:b5;
  __shared__ float es[64 * 64];
  __shared__ float bs[64 * 65];
  for (int i = threadIdx.x; i < 4096; i += 256) es[i] = err[i];
  for (int i = threadIdx.x; i < 4096; i += 256) {
    int o = i >> 6, hh = i & 63;
    bs[o * 65 + hh] = BX[(size_t)o * 512 + hb + hh];
  }
  __syncthreads();
  for (int e = 0; e < 16; ++e) {
    int idx = threadIdx.x + e * 256;
    int b = idx >> 6, hh = idx & 63;
    float s = 0.f;
    for (int o = 0; o < 64; ++o) s += es[b * 64 + o] * bs[o * 65 + hh];
    proj[(size_t)p * 32768 + b * 512 + hb + hh] = s;
  }
}

// =========================== E1T: HpT / RsHpT m-major [512][TB] ===========================
__global__ __launch_bounds__(256)
void e1t(const __bf16* __restrict__ r_h, const __bf16* __restrict__ h_h,
         __bf16* __restrict__ HpT, __bf16* __restrict__ RsHpT)
{
  const int t = blockIdx.y, hb = blockIdx.x * 64;
  const int tid = threadIdx.x;
  __shared__ __bf16 tr[64 * 68];
  float hpv[16], rv[16];
  #pragma unroll
  for (int e = 0; e < 16; ++e) {
    int idx = tid + e * 256;
    int b = idx >> 6, hl = idx & 63;
    hpv[e] = hprev_at(h_h, t * 64 + b, hb + hl);
    rv[e]  = (float)r_h[((size_t)t * 64 + b) * 512 + hb + hl];
  }
  for (int rnd = 0; rnd < 2; ++rnd) {
    __syncthreads();
    #pragma unroll
    for (int e = 0; e < 16; ++e) {
      int idx = tid + e * 256;
      int b = idx >> 6, hl = idx & 63;
      tr[b * 68 + hl] = (__bf16)(rnd == 0 ? hpv[e] : rv[e] * hpv[e]);
    }
    __syncthreads();
    __bf16* dst = (rnd == 0) ? HpT : RsHpT;
    #pragma unroll
    for (int e = 0; e < 16; ++e) {
      int idx = tid + e * 256;
      int hl2 = idx >> 6, b2 = idx & 63;
      dst[(size_t)(hb + hl2) * TBc + t * 64 + b2] = tr[b2 * 68 + hl2];
    }
  }
}

// =========================== K4: P = (G @ W1^T) * mul, G fused, m-major out ==========
__global__ __launch_bounds__(256)
void k4_pgemm(const __bf16* __restrict__ z_h, const __bf16* __restrict__ ht_h,
              const __bf16* __restrict__ r_h, const __bf16* __restrict__ h_h,
              const float* __restrict__ proj, const __bf16* __restrict__ W1b,
              __bf16* __restrict__ P)
{
  const int p = blockIdx.z;
  const int krow0 = blockIdx.x * 128;
  const int n0 = blockIdx.y * 128;
  const int pidx = (p == 0) ? 5 : (p == 1) ? 4 : (p == 2) ? 1 : 0;
  const float* pr = proj + (size_t)pidx * 32768;
  const int tid = threadIdx.x, lane = tid & 63, wv = tid >> 6, q = lane >> 4;
  const int wm = (wv & 1) * 64, wn = (wv >> 1) * 64;
  __shared__ __align__(16) __bf16 Al[128 * 40];
  __shared__ __align__(16) __bf16 Bl[128 * 40];
  f32x4 acc[4][4] = {};
  for (int kt = 0; kt < 16; ++kt) {
    const int h0 = kt * 32;
    __syncthreads();
    #pragma unroll
    for (int e = 0; e < 4; ++e) {
      int idx = tid + e * 256;                 // 0..1023
      int row = idx >> 3, h4 = (idx & 7) * 4;
      int kg = krow0 + row;
      bf16x4 zz = *reinterpret_cast<const bf16x4*>(&z_h[(size_t)kg * 512 + h0 + h4]);
      bf16x4 tt = *reinterpret_cast<const bf16x4*>(&ht_h[(size_t)kg * 512 + h0 + h4]);
      float4 pv = *reinterpret_cast<const float4*>(&pr[(size_t)(kg & 63) * 512 + h0 + h4]);
      float pvv[4] = {pv.x, pv.y, pv.z, pv.w};
      bf16x4 gv;
      #pragma unroll
      for (int j = 0; j < 4; ++j) {
        float sz = 1.f - (float)zz[j];
        float v = pvv[j] * sz;
        if (p < 2) { float h = (float)tt[j]; v *= (1.f - h * h); }
        gv[j] = (__bf16)v;
      }
      *reinterpret_cast<bf16x4*>(&Al[row * 40 + h4]) = gv;
      bf16x4 wv4 = *reinterpret_cast<const bf16x4*>(&W1b[(size_t)(n0 + row) * 512 + h0 + h4]);
      *reinterpret_cast<bf16x4*>(&Bl[row * 40 + h4]) = wv4;
    }
    __syncthreads();
    bf16x8 af[4], bfv[4];
    #pragma unroll
    for (int mi = 0; mi < 4; ++mi)
      af[mi] = *reinterpret_cast<const bf16x8*>(&Al[(wm + mi * 16 + (lane & 15)) * 40 + q * 8]);
    #pragma unroll
    for (int ni = 0; ni < 4; ++ni)
      bfv[ni] = *reinterpret_cast<const bf16x8*>(&Bl[(wn + ni * 16 + (lane & 15)) * 40 + q * 8]);
    #pragma unroll
    for (int mi = 0; mi < 4; ++mi)
      #pragma unroll
      for (int ni = 0; ni < 4; ++ni)
        acc[mi][ni] = __builtin_amdgcn_mfma_f32_16x16x32_bf16(af[mi], bfv[ni], acc[mi][ni], 0, 0, 0);
  }
  __bf16* Pp = P + (size_t)p * THW;
  #pragma unroll
  for (int mi = 0; mi < 4; ++mi) {
    const int kg = krow0 + wm + mi * 16 + q * 4;
    const int tt = kg >> 6;
    #pragma unroll
    for (int ni = 0; ni < 4; ++ni) {
      const int n = n0 + wn + ni * 16 + (lane & 15);
      union { __bf16 b[4]; uint2 u; } pk;
      #pragma unroll
      for (int i = 0; i < 4; ++i) {
        float mul;
        if (p < 2) {
          float r = (float)r_h[(size_t)(kg + i) * 512 + n];
          float hp = 0.f;
          if (tt != 1) {
            int kr = (tt == 0) ? (16320 + (kg & 63) + i) : (kg + i - 128);
            hp = (float)h_h[(size_t)kr * 512 + n];
          }
          mul = hp * r * (1.f - r);
        } else {
          float h = (float)ht_h[(size_t)(kg + i) * 512 + n];
          mul = 1.f - h * h;
        }
        pk.b[i] = (__bf16)(acc[mi][ni][i] * mul);
      }
      *reinterpret_cast<uint2*>(&Pp[(size_t)n * TBc + kg]) = pk.u;
    }
  }
}

// =========================== K5: TN grad GEMM, split-k atomics into d_out ==========
__global__ __launch_bounds__(256)
void k5_grad(const __bf16* __restrict__ Ap, int amode, const __bf16* __restrict__ Bp,
             const __bf16* __restrict__ r_h, const __bf16* __restrict__ ht_h,
             const __bf16* __restrict__ h_h, const float* __restrict__ projA,
             float* __restrict__ out, int N, int klen, float scale)
{
  const int m0 = blockIdx.x * 128;
  const int n0 = blockIdx.y * 128;
  const int tid = threadIdx.x, lane = tid & 63, wv = tid >> 6, q = lane >> 4;
  const int wm = (wv & 1) * 64, wn = (wv >> 1) * 64;
  __shared__ __align__(16) __bf16 Al[128 * 72];
  __shared__ __align__(16) __bf16 Bl[128 * 72];
  f32x4 acc[4][4] = {};
  const int iters = klen >> 6;
  for (int kt = 0; kt < iters; ++kt) {
    const int kk0 = blockIdx.z * klen + kt * 64;
    __syncthreads();
    #pragma unroll
    for (int e = 0; e < 8; ++e) {
      int idx = tid + e * 256;              // 0..2047
      int row = idx >> 4, c4 = (idx & 15) * 4;
      bf16x4 bv = *reinterpret_cast<const bf16x4*>(&Bp[(size_t)(n0 + row) * TBc + kk0 + c4]);
      *reinterpret_cast<bf16x4*>(&Bl[row * 72 + c4]) = bv;
    }
    if (amode == 0) {
      #pragma unroll
      for (int e = 0; e < 8; ++e) {
        int idx = tid + e * 256;
        int row = idx >> 4, c4 = (idx & 15) * 4;
        bf16x4 av = *reinterpret_cast<const bf16x4*>(&Ap[(size_t)(m0 + row) * TBc + kk0 + c4]);
        *reinterpret_cast<bf16x4*>(&Al[row * 72 + c4]) = av;
      }
    } else {
      #pragma unroll
      for (int e = 0; e < 8; ++e) {
        int idx = tid + e * 256;
        int kk = idx >> 5;                  // 0..63 local k row
        int m4 = (idx & 31) * 4;
        int kg = kk0 + kk;
        int tt = kg >> 6;
        bf16x4 hs = *reinterpret_cast<const bf16x4*>(&ht_h[(size_t)kg * 512 + m0 + m4]);
        bf16x4 rv = *reinterpret_cast<const bf16x4*>(&r_h[(size_t)kg * 512 + m0 + m4]);
        float4 pv = *reinterpret_cast<const float4*>(&projA[(size_t)(kg & 63) * 512 + m0 + m4]);
        float pvv[4] = {pv.x, pv.y, pv.z, pv.w};
        float hpf[4] = {0.f, 0.f, 0.f, 0.f};
        if (tt != 1) {
          int kr = (tt == 0) ? (16320 + (kg & 63)) : (kg - 128);
          bf16x4 hp = *reinterpret_cast<const bf16x4*>(&h_h[(size_t)kr * 512 + m0 + m4]);
          #pragma unroll
          for (int j = 0; j < 4; ++j) hpf[j] = (float)hp[j];
        }
        #pragma unroll
        for (int j = 0; j < 4; ++j) {
          float r = (float)rv[j];
          float zg = (hpf[j] - (float)hs[j]) * r * (1.f - r) * pvv[j];
          Al[(m4 + j) * 72 + kk] = (__bf16)zg;
        }
      }
    }
    __syncthreads();
    #pragma unroll
    for (int ks = 0; ks < 2; ++ks) {
      bf16x8 af[4], bfv[4];
      #pragma unroll
      for (int mi = 0; mi < 4; ++mi)
        af[mi] = *reinterpret_cast<const bf16x8*>(&Al[(wm + mi * 16 + (lane & 15)) * 72 + ks * 32 + q * 8]);
      #pragma unroll
      for (int ni = 0; ni < 4; ++ni)
        bfv[ni] = *reinterpret_cast<const bf16x8*>(&Bl[(wn + ni * 16 + (lane & 15)) * 72 + ks * 32 + q * 8]);
      #pragma unroll
      for (int mi = 0; mi < 4; ++mi)
        #pragma unroll
        for (int ni = 0; ni < 4; ++ni)
          acc[mi][ni] = __builtin_amdgcn_mfma_f32_16x16x32_bf16(af[mi], bfv[ni], acc[mi][ni], 0, 0, 0);
    }
  }
  #pragma unroll
  for (int mi = 0; mi < 4; ++mi) {
    const int m = m0 + wm + mi * 16 + q * 4;
    #pragma unroll
    for (int ni = 0; ni < 4; ++ni) {
      const int n = n0 + wn + ni * 16 + (lane & 15);
      #pragma unroll
      for (int i = 0; i < 4; ++i)
        atomicAdd(&out[(size_t)(m + i) * N + n], acc[mi][ni][i] * scale);
    }
  }
}

// =========================== db kernels ===========================
// merged: y=0 -> P-plane 2 (HV) into db[0..511]; y=1 -> P-plane 0 (AV) into db[1024..1535]
__global__ void k_dbP(const __bf16* __restrict__ P, float* __restrict__ db)
{
  const size_t plane = (blockIdx.y == 0) ? 2 : 0;
  const int dbo = (blockIdx.y == 0) ? 0 : 1024;
  const __bf16* row = P + plane * THW + (size_t)blockIdx.x * TBc;
  float sv = 0.f;
  for (int i = threadIdx.x; i < TBc; i += 256) sv += (float)row[i];
  for (int off = 32; off; off >>= 1) sv += __shfl_xor(sv, off, 64);
  __shared__ float red[4];
  if ((threadIdx.x & 63) == 0) red[threadIdx.x >> 6] = sv;
  __syncthreads();
  if (threadIdx.x == 0)
    atomicAdd(&db[dbo + blockIdx.x], (red[0] + red[1] + red[2] + red[3]) * (1.f / 64.f));
}

__global__ void k_dbzg(const __bf16* __restrict__ r_h, const __bf16* __restrict__ ht_h,
                       const __bf16* __restrict__ h_h, const float* __restrict__ proj,
                       float* __restrict__ db)
{
  const int hb = blockIdx.x * 64;
  const int col = hb + (threadIdx.x & 63);
  const int part = threadIdx.x >> 6;
  const int kb = blockIdx.y * 1024;
  float sum = 0.f;
  for (int k = kb + part; k < kb + 1024; k += 4) {
    float hs = (float)ht_h[(size_t)k * 512 + col];
    float r  = (float)r_h[(size_t)k * 512 + col];
    float hp = hprev_at(h_h, k, col);
    float pv = proj[3 * 32768 + (size_t)(k & 63) * 512 + col];
    sum += (hp - hs) * r * (1.f - r) * pv;
  }
  __shared__ float sred[4][64];
  sred[part][threadIdx.x & 63] = sum;
  __syncthreads();
  if (threadIdx.x < 64)
    atomicAdd(&db[512 + hb + threadIdx.x],
              (sred[0][threadIdx.x] + sred[1][threadIdx.x] +
               sred[2][threadIdx.x] + sred[3][threadIdx.x]) * (1.f / 64.f));
}

// =========================== K6: norm + clip (grads live in d_out) ===========================
__global__ void k6a_sumsq(const float* __restrict__ dout, const float* __restrict__ db,
                          float* __restrict__ slots)
{
  const int yy = blockIdx.y;
  const float* src; int count;
  if (yy < 3)      { src = dout + O_DW0 + (size_t)yy * 262144; count = 262144; }
  else if (yy < 6) { src = dout + O_DV0 + (size_t)(yy - 3) * 65536; count = 65536; }
  else             { src = db + (size_t)(yy - 6) * 512; count = 512; }
  int start = blockIdx.x * 4096;
  if (start >= count) return;
  int end = min(start + 4096, count);
  float sp = 0.f;
  for (int i = start + threadIdx.x; i < end; i += 256) { float v = src[i]; sp += v * v; }
  for (int off = 32; off; off >>= 1) sp += __shfl_xor(sp, off, 64);
  __shared__ float red[4];
  if ((threadIdx.x & 63) == 0) red[threadIdx.x >> 6] = sp;
  __syncthreads();
  if (threadIdx.x == 0) atomicAdd(&slots[yy], red[0] + red[1] + red[2] + red[3]);
}

__global__ void k6b_write(const float* __restrict__ db,
                          const float* __restrict__ slots, float* __restrict__ dout)
{
  const int yy = blockIdx.y;
  const float* src; int count; size_t oo;
  if (yy < 3)      { oo = O_DW0 + (size_t)yy * 262144; src = dout + oo; count = 262144; }
  else if (yy < 6) { oo = O_DV0 + (size_t)(yy - 3) * 65536; src = dout + oo; count = 65536; }
  else             { oo = O_DB0 + (size_t)(yy - 6) * 512; src = db + (size_t)(yy - 6) * 512; count = 512; }
  int start = blockIdx.x * 4096;
  if (start >= count) return;
  int end = min(start + 4096, count);
  float inv = 1.f / sqrtf(slots[yy]);
  for (int i = start + threadIdx.x; i < end; i += 256) {
    float v = src[i] * inv;
    dout[oo + i] = fminf(fmaxf(v, -5.f), 5.f);
  }
}

// =========================== launch ===========================
extern "C" void kernel_launch(void* const* d_in, const int* in_sizes, int n_in,
                              void* d_out, int out_size, void* d_ws, size_t ws_size,
                              hipStream_t stream)
{
  const float* x     = (const float*)d_in[0];
  const int*   y     = (const int*)d_in[1];
  const float* W1w   = (const float*)d_in[2];
  const float* V1w   = (const float*)d_in[3];
  const float* V1b   = (const float*)d_in[4];
  const float* W2w   = (const float*)d_in[5];
  const float* W2b   = (const float*)d_in[6];
  const float* V2w   = (const float*)d_in[7];
  const float* W3w   = (const float*)d_in[8];
  const float* W3b   = (const float*)d_in[9];
  const float* V3w   = (const float*)d_in[10];
  const float* Woutw = (const float*)d_in[11];
  const float* Woutb = (const float*)d_in[12];
  const float* BW1   = (const float*)d_in[13];
  const float* BV1   = (const float*)d_in[14];
  const float* BW2   = (const float*)d_in[15];
  const float* BV2   = (const float*)d_in[16];
  const float* BW3   = (const float*)d_in[17];
  const float* BV3   = (const float*)d_in[18];
  float* dout = (float*)d_out;
  char* ws = (char*)d_ws;

  if (ws_size < W_NEED) { ksent<<<1, 1, 0, stream>>>(dout, (float)ws_size); return; }

  float*  slots = (float*)(ws + W_SLOT);
  float*  dbr   = (float*)(ws + W_DB);
  float*  errw  = (float*)(ws + W_ERRW);
  float*  proj  = (float*)(ws + W_PROJ);
  unsigned int* exch = (unsigned int*)(ws + W_EXCH);
  __bf16* W1b   = (__bf16*)(ws + W_W1B);
  __bf16* XT    = (__bf16*)(ws + W_XT);
  __bf16* r_h   = (__bf16*)(ws + W_HIST);
  __bf16* z_h   = (__bf16*)(ws + W_HIST + 16777216);
  __bf16* ht_h  = (__bf16*)(ws + W_HIST + 33554432);
  __bf16* h_h   = (__bf16*)(ws + W_HIST + 50331648);
  char*   PB    = ws + W_PB;

  // xV fp32 (dead after k2) aliases P/HpT/RsHpT (live after k2)
  float* xv1 = (float*)PB;
  float* xv2 = (float*)(PB + 33554432);
  float* xv3 = (float*)(PB + 67108864);
  __bf16* P     = (__bf16*)PB;                     // 4 x [512][TB] bf16 = 67.1 MB
  __bf16* HpT   = (__bf16*)(PB + 67108864);
  __bf16* RsHpT = (__bf16*)(PB + 83886080);

  kzero<<<16, 256, 0, stream>>>((float*)ws, 4096);                  // slots+dbr(+pad)
  kzero<<<768, 256, 0, stream>>>((float*)(ws + W_EXCH), 196608);    // exchange epochs -> 0
  kzero<<<3840, 256, 0, stream>>>(dout + O_DW0, 983040);            // grad accumulators
  k1_xv<<<dim3(24, 256), 256, 0, stream>>>(x, V1w, V2w, V3w, V1b, W2b, W3b, xv1, xv2, xv3);
  e0_xt<<<256, 256, 0, stream>>>(x, XT);
  k2_recur<<<64, 256, 0, stream>>>(W1w, W2w, W3w, xv1, xv2, xv3,
                                   r_h, z_h, ht_h, h_h, exch, dout);
  k0_cast<<<1024, 256, 0, stream>>>(W1w, W1b, 262144);   // after k2 (W1b aliases exch)
  k3a_soft<<<64, 64, 0, stream>>>(Woutw, Woutb, y, dout, errw);
  k3b_proj<<<dim3(8, 6), 256, 0, stream>>>(errw, BW1, BV1, BW2, BV2, BW3, BV3, proj);
  e1t<<<dim3(8, 256), 256, 0, stream>>>(r_h, h_h, HpT, RsHpT);
  k_dbzg<<<dim3(8, 16), 256, 0, stream>>>(r_h, ht_h, h_h, proj, dbr);   // db1

  k4_pgemm<<<dim3(128, 4, 4), 256, 0, stream>>>(z_h, ht_h, r_h, h_h, proj, W1b, P);
  const float sc = 1.f / 64.f;
  // dW0 = HW^T @ RsHp ; dW1 = zgW^T @ Hp ; dW2 = AW^T @ Hp
  k5_grad<<<dim3(4, 4, 16), 256, 0, stream>>>(P + 3 * THW, 0, RsHpT, r_h, ht_h, h_h, proj,
                                              dout + O_DW0, 512, 1024, sc);
  k5_grad<<<dim3(4, 4, 16), 256, 0, stream>>>(nullptr, 1, HpT, r_h, ht_h, h_h, proj + 2 * 32768,
                                              dout + O_DW0 + 262144, 512, 1024, sc);
  k5_grad<<<dim3(4, 4, 16), 256, 0, stream>>>(P + 1 * THW, 0, HpT, r_h, ht_h, h_h, proj,
                                              dout + O_DW0 + 524288, 512, 1024, sc);
  // dV0 = HV^T @ X ; dV1 = zgV^T @ X ; dV2 = AV^T @ X
  k5_grad<<<dim3(4, 1, 16), 256, 0, stream>>>(P + 2 * THW, 0, XT, r_h, ht_h, h_h, proj,
                                              dout + O_DV0, 128, 1024, sc);
  k5_grad<<<dim3(4, 1, 16), 256, 0, stream>>>(nullptr, 1, XT, r_h, ht_h, h_h, proj + 3 * 32768,
                                              dout + O_DV0 + 65536, 128, 1024, sc);
  k5_grad<<<dim3(4, 1, 16), 256, 0, stream>>>(P + 0 * THW, 0, XT, r_h, ht_h, h_h, proj,
                                              dout + O_DV0 + 131072, 128, 1024, sc);
  k_dbP<<<dim3(512, 2), 256, 0, stream>>>(P, dbr);             // db0 (HV) + db2 (AV)
  k6a_sumsq<<<dim3(64, 9), 256, 0, stream>>>(dout, dbr, slots);
  k6b_write<<<dim3(64, 9), 256, 0, stream>>>(dbr, slots, dout);
}

// Round 6
// 2582.757 us; speedup vs baseline: 3.0272x; 3.0272x over previous
//
#include <hip/hip_runtime.h>
#include <hip/hip_bf16.h>

#define DI __device__ __forceinline__

typedef __bf16 bf16x8 __attribute__((ext_vector_type(8)));
typedef __bf16 bf16x4 __attribute__((ext_vector_type(4)));
typedef __bf16 bf16x2 __attribute__((ext_vector_type(2)));
typedef float  f32x4  __attribute__((ext_vector_type(4)));
typedef unsigned long long ull;

static constexpr int Bc = 64, Tc = 256, Ic = 128, Hc = 512, Oc = 64;
static constexpr int TBc = Tc * Bc;                 // 16384
static constexpr size_t THW = (size_t)TBc * Hc;     // 8388608 elems

// ---------- d_out offsets (floats) ----------
static constexpr size_t O_OUT = 0;
static constexpr size_t O_HT  = 4096;
static constexpr size_t O_DW0 = 36864;
static constexpr size_t O_DV0 = 823296;
static constexpr size_t O_DB0 = 1019904;
static constexpr size_t O_ERR = 1021440;

// ---------- ws offsets (bytes) ----------
static constexpr size_t W_SLOT = 1024;     // 9 f32
static constexpr size_t W_DB   = 2048;     // db_raw [3][512] f32 -> ends 8192
static constexpr size_t W_FLG  = 8192;     // barrier epoch flags: 64 slots x 128B -> ends 16384
static constexpr size_t W_ERRW = 16384;    // error [64][64] f32
static constexpr size_t W_PROJ = 32768;    // proj [6][64][512] f32 -> ends 819200
static constexpr size_t W_W1B  = 819200;   // W1 bf16 [512][512] -> ends 1343488
static constexpr size_t W_HX   = 1343488;  // h exchange fp32 [4][8192] (128 KB)
static constexpr size_t W_HRX  = 1474560;  // hr exchange fp32 [4][8192] -> ends 1605632
static constexpr size_t W_XT   = 1605632;  // x^T bf16 [128][TB] -> ends 5799936
static constexpr size_t W_HIST = 5799936;  // r,z,ht,h bf16 [TB][512] each -> ends 72908800
static constexpr size_t W_PB   = 72908800; // xV fp32 (100.6MB) / later P + HpT + RsHpT
static constexpr size_t W_NEED = W_PB + 100663296;   // 173572096

// =========================== helpers ===========================

DI void st32_agent(float* p, float v) {
  __hip_atomic_store((unsigned int*)p, __float_as_uint(v),
                     __ATOMIC_RELAXED, __HIP_MEMORY_SCOPE_AGENT);
}
DI ull ld64_agent(const void* p) {
  return __hip_atomic_load((ull*)p, __ATOMIC_RELAXED, __HIP_MEMORY_SCOPE_AGENT);
}

// Fence-free group barrier via distributed epoch flags. Each wg STORES the
// epoch to its own 128B-strided slot (no RMW); wave 0 polls all 16 slots with
// 16 parallel lanes. The leading __syncthreads() emits s_waitcnt vmcnt(0) per
// wave, draining the agent-scope exchange stores before the flag store.
// History stores are deliberately issued AFTER this barrier so they are not
// part of the drained set (R6: they are only consumed post-k2).
DI void group_barrier(int* flags_g, int myslot, int bar, bool& dead) {
  __syncthreads();
  if (threadIdx.x == 0)
    __hip_atomic_store(&flags_g[myslot * 32], bar,
                       __ATOMIC_RELAXED, __HIP_MEMORY_SCOPE_AGENT);
  if (threadIdx.x < 64 && !dead) {
    const int l = threadIdx.x;
    int spins = 0;
    for (;;) {
      int v = bar;
      if (l < 16)
        v = __hip_atomic_load(&flags_g[l * 32],
                              __ATOMIC_RELAXED, __HIP_MEMORY_SCOPE_AGENT);
      if (__all(v >= bar)) break;
      __builtin_amdgcn_s_sleep(1);
      if (++spins > 4000000) { dead = true; break; }   // never hang the bench
    }
  }
  __syncthreads();
}

// hiddens[t-1] with python-negative-index quirk; k = t*64+b
DI float hprev_at(const __bf16* __restrict__ h_h, int k, int col) {
  int t = k >> 6;
  if (t == 1) return 0.f;
  int row = (t == 0) ? (16320 + (k & 63)) : (k - 128);
  return (float)h_h[(size_t)row * 512 + col];
}

// =========================== tiny kernels ===========================

__global__ void kzero(float* __restrict__ p, int n) {
  int i = blockIdx.x * 256 + threadIdx.x;
  if (i < n) p[i] = 0.f;
}
__global__ void ksent(float* p, float v) { p[0] = v; }
__global__ void k0_cast(const float* __restrict__ s, __bf16* __restrict__ d, int n) {
  int i = blockIdx.x * 256 + threadIdx.x;
  if (i < n) d[i] = (__bf16)s[i];
}

// =========================== K1: xV = x@V^T + bias (fp32) ===========================
__global__ __launch_bounds__(256)
void k1_xv(const float* __restrict__ x, const float* __restrict__ V1w,
           const float* __restrict__ V2w, const float* __restrict__ V3w,
           const float* __restrict__ V1b, const float* __restrict__ W2b,
           const float* __restrict__ W3b,
           float* __restrict__ xv1f, float* __restrict__ xv2f, float* __restrict__ xv3f)
{
  const int cb = blockIdx.x, t = blockIdx.y;
  const int g = cb >> 3, jblk = cb & 7;
  const float* Vg   = (g == 0) ? V1w : (g == 1) ? V2w : V3w;
  const float* bias = (g == 0) ? V1b : (g == 1) ? W2b : W3b;
  float* of = (g == 0) ? xv1f : (g == 1) ? xv2f : xv3f;
  __shared__ float As[64 * 69];
  __shared__ float Bs[64 * 69];
  const int tid = threadIdx.x;
  float acc[4][4] = {};
  const int m0 = (tid & 15) * 4, j0 = (tid >> 4) * 4;
  for (int kc = 0; kc < 2; ++kc) {
    __syncthreads();
    #pragma unroll
    for (int e = 0; e < 4; ++e) {
      int idx = tid + e * 256;            // 0..1023
      int row = idx >> 4, c4 = (idx & 15) * 4;
      float4 v = *reinterpret_cast<const float4*>(&x[((size_t)row * 256 + t) * 128 + kc * 64 + c4]);
      As[row * 69 + c4 + 0] = v.x; As[row * 69 + c4 + 1] = v.y;
      As[row * 69 + c4 + 2] = v.z; As[row * 69 + c4 + 3] = v.w;
      float4 w = *reinterpret_cast<const float4*>(&Vg[(size_t)(jblk * 64 + row) * 128 + kc * 64 + c4]);
      Bs[row * 69 + c4 + 0] = w.x; Bs[row * 69 + c4 + 1] = w.y;
      Bs[row * 69 + c4 + 2] = w.z; Bs[row * 69 + c4 + 3] = w.w;
    }
    __syncthreads();
    for (int i = 0; i < 64; ++i) {
      float a[4], b[4];
      #pragma unroll
      for (int u = 0; u < 4; ++u) a[u] = As[(m0 + u) * 69 + i];
      #pragma unroll
      for (int u = 0; u < 4; ++u) b[u] = Bs[(j0 + u) * 69 + i];
      #pragma unroll
      for (int mi = 0; mi < 4; ++mi)
        #pragma unroll
        for (int ji = 0; ji < 4; ++ji) acc[mi][ji] += a[mi] * b[ji];
    }
  }
  #pragma unroll
  for (int ji = 0; ji < 4; ++ji) {
    int jg = jblk * 64 + j0 + ji;
    float bv = bias[jg];
    #pragma unroll
    for (int mi = 0; mi < 4; ++mi) {
      int b = m0 + mi;
      of[((size_t)t * 64 + b) * 512 + jg] = acc[mi][ji] + bv;
    }
  }
}

// =========================== E0: X^T bf16 [128][TB] ===========================
__global__ void e0_xt(const float* __restrict__ x, __bf16* __restrict__ XT)
{
  const int t = blockIdx.x;
  __shared__ __bf16 xs[64 * 132];
  const int tid = threadIdx.x;
  #pragma unroll
  for (int e = 0; e < 8; ++e) {
    int idx = tid + e * 256;              // 0..2047
    int b = idx >> 5, c4 = (idx & 31) * 4;
    float4 v = *reinterpret_cast<const float4*>(&x[((size_t)b * 256 + t) * 128 + c4]);
    xs[b * 132 + c4 + 0] = (__bf16)v.x; xs[b * 132 + c4 + 1] = (__bf16)v.y;
    xs[b * 132 + c4 + 2] = (__bf16)v.z; xs[b * 132 + c4 + 3] = (__bf16)v.w;
  }
  __syncthreads();
  #pragma unroll
  for (int e = 0; e < 8; ++e) {
    int idx = tid + e * 256;
    int i = idx >> 4, b4 = (idx & 15) * 4;
    __bf16* d = &XT[(size_t)i * TBc + t * 64 + b4];
    d[0] = xs[(b4 + 0) * 132 + i];
    d[1] = xs[(b4 + 1) * 132 + i];
    d[2] = xs[(b4 + 2) * 132 + i];
    d[3] = xs[(b4 + 3) * 132 + i];
  }
}

// =========================== K2: persistent GRU recurrence, fp32-faithful =========
// 64 wgs = 4 batch-groups(16 rows) x 16 col-wgs(32 cols). 4 waves/wg =
// 2 col-tiles x 2 k-halves (8 kk each). Both operands split 3-way bf16
// (24-bit mantissa, Ootomo 6-term MFMA, residual ~2^-24). h exchanged fp32.
// Exchange layout == LDS fragment layout (identity): lane-consecutive 8B
// loads, conflict-free 4B-stride ds_writes. pbuf lane stride 9 (conflict-free).
// R6: history stores issued AFTER the barrier (off the vmcnt drain path);
// final dead stage skipped.
__global__ __launch_bounds__(256, 1)
void k2_recur(const float* __restrict__ W1w, const float* __restrict__ W2w,
              const float* __restrict__ W3w,
              const float* __restrict__ xv1, const float* __restrict__ xv2,
              const float* __restrict__ xv3,
              __bf16* __restrict__ r_h, __bf16* __restrict__ z_h,
              __bf16* __restrict__ ht_h, __bf16* __restrict__ h_h,
              float* __restrict__ hx, float* __restrict__ hrx,
              int* __restrict__ flags, float* __restrict__ dout)
{
  const int g  = blockIdx.x >> 4;      // batch group 0..3
  const int cw = blockIdx.x & 15;      // col-wg 0..15
  const int tid = threadIdx.x, lane = tid & 63, wv = tid >> 6;
  const int kh = wv & 1;               // k-half
  const int ct = wv >> 1;              // col-tile
  const int q  = lane >> 4;
  const int colc = cw * 32 + ct * 16 + (lane & 15);
  const bool owner = (kh == 0);

  __shared__ __align__(16) __bf16 c0[8192];   // h comp0 frags [16kk][64lane][8]
  __shared__ __align__(16) __bf16 c1[8192];
  __shared__ __align__(16) __bf16 c2[8192];
  __shared__ float pbuf[128 * 9];             // cross-wave partials, 9-stride

  // weight fragments, 3-way split: lane n=colc, k = (kh*8+kk2)*32 + q*8 + j
  bf16x8 w1c[3][8], w2c[3][8], w3c[3][8];
  #pragma unroll
  for (int kk2 = 0; kk2 < 8; ++kk2) {
    const int kb = (kh * 8 + kk2) * 32 + q * 8;
    #pragma unroll
    for (int j = 0; j < 8; ++j) {
      float w = W1w[(size_t)colc * 512 + kb + j];
      __bf16 a = (__bf16)w; float r1 = w - (float)a;
      __bf16 b = (__bf16)r1;
      w1c[0][kk2][j] = a; w1c[1][kk2][j] = b; w1c[2][kk2][j] = (__bf16)(r1 - (float)b);
      w = W2w[(size_t)colc * 512 + kb + j];
      a = (__bf16)w; r1 = w - (float)a; b = (__bf16)r1;
      w2c[0][kk2][j] = a; w2c[1][kk2][j] = b; w2c[2][kk2][j] = (__bf16)(r1 - (float)b);
      w = W3w[(size_t)colc * 512 + kb + j];
      a = (__bf16)w; r1 = w - (float)a; b = (__bf16)r1;
      w3c[0][kk2][j] = a; w3c[1][kk2][j] = b; w3c[2][kk2][j] = (__bf16)(r1 - (float)b);
    }
  }
  for (int i = tid; i < 8192; i += 256) {
    c0[i] = (__bf16)0.f; c1[i] = (__bf16)0.f; c2[i] = (__bf16)0.f;
  }
  __syncthreads();

  float hreg[4] = {0.f, 0.f, 0.f, 0.f};
  float* hx_g  = hx  + g * 8192;
  float* hrx_g = hrx + g * 8192;
  int* flags_g = flags + g * 16 * 32;
  // frag index for state element (m=q*4+i, c=colc)
  const int fragbase = (colc >> 5) * 512 + (((colc >> 3) & 3) * 16 + q * 4) * 8 + (colc & 7);
  const int pb = (ct * 64 + lane) * 9;

  // coalesced exchange reload: lane-consecutive ull loads, identity map to
  // the c0/c1/c2 fragment layout (LDS byte offset = 4 * ull index).
  auto stage = [&](const float* __restrict__ srcf) {
    const ull* src = reinterpret_cast<const ull*>(srcf);
    ull u[16];
    #pragma unroll
    for (int j = 0; j < 16; ++j) u[j] = ld64_agent(src + j * 256 + tid);
    #pragma unroll
    for (int j = 0; j < 16; ++j) {
      float f0 = __uint_as_float((unsigned int)u[j]);
      float f1 = __uint_as_float((unsigned int)(u[j] >> 32));
      __bf16 a0 = (__bf16)f0; float r0 = f0 - (float)a0; __bf16 b0 = (__bf16)r0;
      __bf16 d0 = (__bf16)(r0 - (float)b0);
      __bf16 a1 = (__bf16)f1; float r1 = f1 - (float)a1; __bf16 b1 = (__bf16)r1;
      __bf16 d1 = (__bf16)(r1 - (float)b1);
      int o = (j * 256 + tid) * 2;
      bf16x2 v0; v0[0] = a0; v0[1] = a1;
      bf16x2 v1; v1[0] = b0; v1[1] = b1;
      bf16x2 v2; v2[0] = d0; v2[1] = d1;
      *reinterpret_cast<bf16x2*>(&c0[o]) = v0;
      *reinterpret_cast<bf16x2*>(&c1[o]) = v1;
      *reinterpret_cast<bf16x2*>(&c2[o]) = v2;
    }
  };

  bool dead = false;
  int bar = 0;
  #pragma unroll 1
  for (int t = 0; t < Tc; ++t) {
    const size_t rowb = ((size_t)t * 64 + g * 16 + q * 4) * 512 + colc;
    float xv1v[4], xv2v[4], xv3v[4];
    if (owner) {
      #pragma unroll
      for (int i = 0; i < 4; ++i) {
        size_t o = rowb + (size_t)i * 512;
        xv1v[i] = xv1[o]; xv2v[i] = xv2[o]; xv3v[i] = xv3[o];
      }
    }
    // ---- phase 1: z, r gates ----
    f32x4 a2 = {0.f,0.f,0.f,0.f}, a3 = {0.f,0.f,0.f,0.f};
    #pragma unroll
    for (int kk2 = 0; kk2 < 8; ++kk2) {
      const int idx = (kh * 8 + kk2) * 512 + lane * 8;
      bf16x8 h0 = *reinterpret_cast<const bf16x8*>(&c0[idx]);
      bf16x8 h1 = *reinterpret_cast<const bf16x8*>(&c1[idx]);
      bf16x8 h2 = *reinterpret_cast<const bf16x8*>(&c2[idx]);
      a2 = __builtin_amdgcn_mfma_f32_16x16x32_bf16(h0, w2c[0][kk2], a2, 0, 0, 0);
      a2 = __builtin_amdgcn_mfma_f32_16x16x32_bf16(h1, w2c[0][kk2], a2, 0, 0, 0);
      a2 = __builtin_amdgcn_mfma_f32_16x16x32_bf16(h0, w2c[1][kk2], a2, 0, 0, 0);
      a2 = __builtin_amdgcn_mfma_f32_16x16x32_bf16(h2, w2c[0][kk2], a2, 0, 0, 0);
      a2 = __builtin_amdgcn_mfma_f32_16x16x32_bf16(h1, w2c[1][kk2], a2, 0, 0, 0);
      a2 = __builtin_amdgcn_mfma_f32_16x16x32_bf16(h0, w2c[2][kk2], a2, 0, 0, 0);
      a3 = __builtin_amdgcn_mfma_f32_16x16x32_bf16(h0, w3c[0][kk2], a3, 0, 0, 0);
      a3 = __builtin_amdgcn_mfma_f32_16x16x32_bf16(h1, w3c[0][kk2], a3, 0, 0, 0);
      a3 = __builtin_amdgcn_mfma_f32_16x16x32_bf16(h0, w3c[1][kk2], a3, 0, 0, 0);
      a3 = __builtin_amdgcn_mfma_f32_16x16x32_bf16(h2, w3c[0][kk2], a3, 0, 0, 0);
      a3 = __builtin_amdgcn_mfma_f32_16x16x32_bf16(h1, w3c[1][kk2], a3, 0, 0, 0);
      a3 = __builtin_amdgcn_mfma_f32_16x16x32_bf16(h0, w3c[2][kk2], a3, 0, 0, 0);
    }
    if (!owner) {
      #pragma unroll
      for (int i = 0; i < 4; ++i) { pbuf[pb + i] = a2[i]; pbuf[pb + 4 + i] = a3[i]; }
    }
    __syncthreads();
    float zz[4], rr4[4];
    if (owner) {
      // exchange stores only (they gate the barrier drain)
      #pragma unroll
      for (int i = 0; i < 4; ++i) {
        float s2 = a2[i] + pbuf[pb + i]     + xv2v[i];
        float s3 = a3[i] + pbuf[pb + 4 + i] + xv3v[i];
        zz[i]  = 1.f / (1.f + expf(-s2));
        rr4[i] = 1.f / (1.f + expf(-s3));
        st32_agent(&hrx_g[fragbase + i * 8], hreg[i] * rr4[i]);
      }
    }
    ++bar; group_barrier(flags_g, cw, bar, dead);
    // history stores AFTER the flag: their drain overlaps the stage loads
    if (owner) {
      #pragma unroll
      for (int i = 0; i < 4; ++i) {
        z_h[rowb + (size_t)i * 512] = (__bf16)zz[i];
        r_h[rowb + (size_t)i * 512] = (__bf16)rr4[i];
      }
    }
    stage(hrx_g);
    __syncthreads();
    // ---- phase 2: candidate + update ----
    f32x4 a1 = {0.f,0.f,0.f,0.f};
    #pragma unroll
    for (int kk2 = 0; kk2 < 8; ++kk2) {
      const int idx = (kh * 8 + kk2) * 512 + lane * 8;
      bf16x8 h0 = *reinterpret_cast<const bf16x8*>(&c0[idx]);
      bf16x8 h1 = *reinterpret_cast<const bf16x8*>(&c1[idx]);
      bf16x8 h2 = *reinterpret_cast<const bf16x8*>(&c2[idx]);
      a1 = __builtin_amdgcn_mfma_f32_16x16x32_bf16(h0, w1c[0][kk2], a1, 0, 0, 0);
      a1 = __builtin_amdgcn_mfma_f32_16x16x32_bf16(h1, w1c[0][kk2], a1, 0, 0, 0);
      a1 = __builtin_amdgcn_mfma_f32_16x16x32_bf16(h0, w1c[1][kk2], a1, 0, 0, 0);
      a1 = __builtin_amdgcn_mfma_f32_16x16x32_bf16(h2, w1c[0][kk2], a1, 0, 0, 0);
      a1 = __builtin_amdgcn_mfma_f32_16x16x32_bf16(h1, w1c[1][kk2], a1, 0, 0, 0);
      a1 = __builtin_amdgcn_mfma_f32_16x16x32_bf16(h0, w1c[2][kk2], a1, 0, 0, 0);
    }
    if (!owner) {
      #pragma unroll
      for (int i = 0; i < 4; ++i) pbuf[pb + i] = a1[i];
    }
    __syncthreads();
    float htv[4];
    if (owner) {
      #pragma unroll
      for (int i = 0; i < 4; ++i) {
        float pre = a1[i] + pbuf[pb + i] + xv1v[i];
        float ht = tanhf(pre);
        float hn = zz[i] * (hreg[i] - ht) + ht;
        htv[i] = ht;
        hreg[i] = hn;
        st32_agent(&hx_g[fragbase + i * 8], hn);
      }
    }
    ++bar; group_barrier(flags_g, cw, bar, dead);
    if (owner) {
      #pragma unroll
      for (int i = 0; i < 4; ++i) {
        ht_h[rowb + (size_t)i * 512] = (__bf16)htv[i];
        h_h[rowb + (size_t)i * 512]  = (__bf16)hreg[i];
      }
    }
    if (t + 1 < Tc) stage(hx_g);
    __syncthreads();
  }
  if (owner) {
    #pragma unroll
    for (int i = 0; i < 4; ++i) {
      int b = g * 16 + q * 4 + i;
      dout[O_HT + (size_t)b * 512 + colc] = hreg[i];
    }
  }
}

// =========================== K3a: logits/softmax/error ===========================
__global__ void k3a_soft(const float* __restrict__ Woutw, const float* __restrict__ Woutb,
                         const int* __restrict__ y, float* __restrict__ dout,
                         float* __restrict__ errw)
{
  const int b = blockIdx.x, o = threadIdx.x;
  const float* hrow = dout + O_HT + (size_t)b * 512;
  float sv = Woutb[o];
  for (int k = 0; k < 512; ++k) sv += hrow[k] * Woutw[(size_t)o * 512 + k];
  float mx = sv;
  for (int off = 32; off; off >>= 1) mx = fmaxf(mx, __shfl_xor(mx, off, 64));
  float e = expf(sv - mx);
  float sum = e;
  for (int off = 32; off; off >>= 1) sum += __shfl_xor(sum, off, 64);
  float outp = e / sum;
  float errv = outp - ((y[b] == o) ? 1.f : 0.f);
  dout[O_OUT + b * 64 + o] = outp;
  dout[O_ERR + b * 64 + o] = errv;
  errw[b * 64 + o] = errv;
}

// =========================== K3b: 6 DFA projections ===========================
__global__ __launch_bounds__(256)
void k3b_proj(const float* __restrict__ err,
              const float* b0, const float* b1, const float* b2,
              const float* b3, const float* b4, const float* b5,
              float* __restrict__ proj)
{
  const int p = blockIdx.y;
  const int hb = blockIdx.x * 64;
  const float* BX = (p==0)?b0:(p==1)?b1:(p==2)?b2:(p==3)?b3:(p==4)?b4:b5;
  __shared__ float es[64 * 64];
  __shared__ float bs[64 * 65];
  for (int i = threadIdx.x; i < 4096; i += 256) es[i] = err[i];
  for (int i = threadIdx.x; i < 4096; i += 256) {
    int o = i >> 6, hh = i & 63;
    bs[o * 65 + hh] = BX[(size_t)o * 512 + hb + hh];
  }
  __syncthreads();
  for (int e = 0; e < 16; ++e) {
    int idx = threadIdx.x + e * 256;
    int b = idx >> 6, hh = idx & 63;
    float s = 0.f;
    for (int o = 0; o < 64; ++o) s += es[b * 64 + o] * bs[o * 65 + hh];
    proj[(size_t)p * 32768 + b * 512 + hb + hh] = s;
  }
}

// =========================== E1T: HpT / RsHpT m-major [512][TB] ===========================
__global__ __launch_bounds__(256)
void e1t(const __bf16* __restrict__ r_h, const __bf16* __restrict__ h_h,
         __bf16* __restrict__ HpT, __bf16* __restrict__ RsHpT)
{
  const int t = blockIdx.y, hb = blockIdx.x * 64;
  const int tid = threadIdx.x;
  __shared__ __bf16 tr[64 * 68];
  float hpv[16], rv[16];
  #pragma unroll
  for (int e = 0; e < 16; ++e) {
    int idx = tid + e * 256;
    int b = idx >> 6, hl = idx & 63;
    hpv[e] = hprev_at(h_h, t * 64 + b, hb + hl);
    rv[e]  = (float)r_h[((size_t)t * 64 + b) * 512 + hb + hl];
  }
  for (int rnd = 0; rnd < 2; ++rnd) {
    __syncthreads();
    #pragma unroll
    for (int e = 0; e < 16; ++e) {
      int idx = tid + e * 256;
      int b = idx >> 6, hl = idx & 63;
      tr[b * 68 + hl] = (__bf16)(rnd == 0 ? hpv[e] : rv[e] * hpv[e]);
    }
    __syncthreads();
    __bf16* dst = (rnd == 0) ? HpT : RsHpT;
    #pragma unroll
    for (int e = 0; e < 16; ++e) {
      int idx = tid + e * 256;
      int hl2 = idx >> 6, b2 = idx & 63;
      dst[(size_t)(hb + hl2) * TBc + t * 64 + b2] = tr[b2 * 68 + hl2];
    }
  }
}

// =========================== K4: P = (G @ W1^T) * mul, G fused, m-major out ==========
__global__ __launch_bounds__(256)
void k4_pgemm(const __bf16* __restrict__ z_h, const __bf16* __restrict__ ht_h,
              const __bf16* __restrict__ r_h, const __bf16* __restrict__ h_h,
              const float* __restrict__ proj, const __bf16* __restrict__ W1b,
              __bf16* __restrict__ P)
{
  const int p = blockIdx.z;
  const int krow0 = blockIdx.x * 128;
  const int n0 = blockIdx.y * 128;
  const int pidx = (p == 0) ? 5 : (p == 1) ? 4 : (p == 2) ? 1 : 0;
  const float* pr = proj + (size_t)pidx * 32768;
  const int tid = threadIdx.x, lane = tid & 63, wv = tid >> 6, q = lane >> 4;
  const int wm = (wv & 1) * 64, wn = (wv >> 1) * 64;
  __shared__ __align__(16) __bf16 Al[128 * 40];
  __shared__ __align__(16) __bf16 Bl[128 * 40];
  f32x4 acc[4][4] = {};
  for (int kt = 0; kt < 16; ++kt) {
    const int h0 = kt * 32;
    __syncthreads();
    #pragma unroll
    for (int e = 0; e < 4; ++e) {
      int idx = tid + e * 256;                 // 0..1023
      int row = idx >> 3, h4 = (idx & 7) * 4;
      int kg = krow0 + row;
      bf16x4 zz = *reinterpret_cast<const bf16x4*>(&z_h[(size_t)kg * 512 + h0 + h4]);
      bf16x4 tt = *reinterpret_cast<const bf16x4*>(&ht_h[(size_t)kg * 512 + h0 + h4]);
      float4 pv = *reinterpret_cast<const float4*>(&pr[(size_t)(kg & 63) * 512 + h0 + h4]);
      float pvv[4] = {pv.x, pv.y, pv.z, pv.w};
      bf16x4 gv;
      #pragma unroll
      for (int j = 0; j < 4; ++j) {
        float sz = 1.f - (float)zz[j];
        float v = pvv[j] * sz;
        if (p < 2) { float h = (float)tt[j]; v *= (1.f - h * h); }
        gv[j] = (__bf16)v;
      }
      *reinterpret_cast<bf16x4*>(&Al[row * 40 + h4]) = gv;
      bf16x4 wv4 = *reinterpret_cast<const bf16x4*>(&W1b[(size_t)(n0 + row) * 512 + h0 + h4]);
      *reinterpret_cast<bf16x4*>(&Bl[row * 40 + h4]) = wv4;
    }
    __syncthreads();
    bf16x8 af[4], bfv[4];
    #pragma unroll
    for (int mi = 0; mi < 4; ++mi)
      af[mi] = *reinterpret_cast<const bf16x8*>(&Al[(wm + mi * 16 + (lane & 15)) * 40 + q * 8]);
    #pragma unroll
    for (int ni = 0; ni < 4; ++ni)
      bfv[ni] = *reinterpret_cast<const bf16x8*>(&Bl[(wn + ni * 16 + (lane & 15)) * 40 + q * 8]);
    #pragma unroll
    for (int mi = 0; mi < 4; ++mi)
      #pragma unroll
      for (int ni = 0; ni < 4; ++ni)
        acc[mi][ni] = __builtin_amdgcn_mfma_f32_16x16x32_bf16(af[mi], bfv[ni], acc[mi][ni], 0, 0, 0);
  }
  __bf16* Pp = P + (size_t)p * THW;
  #pragma unroll
  for (int mi = 0; mi < 4; ++mi) {
    const int kg = krow0 + wm + mi * 16 + q * 4;
    const int tt = kg >> 6;
    #pragma unroll
    for (int ni = 0; ni < 4; ++ni) {
      const int n = n0 + wn + ni * 16 + (lane & 15);
      union { __bf16 b[4]; uint2 u; } pk;
      #pragma unroll
      for (int i = 0; i < 4; ++i) {
        float mul;
        if (p < 2) {
          float r = (float)r_h[(size_t)(kg + i) * 512 + n];
          float hp = 0.f;
          if (tt != 1) {
            int kr = (tt == 0) ? (16320 + (kg & 63) + i) : (kg + i - 128);
            hp = (float)h_h[(size_t)kr * 512 + n];
          }
          mul = hp * r * (1.f - r);
        } else {
          float h = (float)ht_h[(size_t)(kg + i) * 512 + n];
          mul = 1.f - h * h;
        }
        pk.b[i] = (__bf16)(acc[mi][ni][i] * mul);
      }
      *reinterpret_cast<uint2*>(&Pp[(size_t)n * TBc + kg]) = pk.u;
    }
  }
}

// =========================== K5: merged TN grad GEMMs (6 jobs, 960 blocks) ==========
// blocks 0..767: dW jobs 0..2 (grid 4x4x16 each); 768..959: dV jobs 0..2 (4x1x16).
// Same per-job tile math & split-k atomics as the former 6 separate launches;
// one launch removes 5 launch gaps and fills dW-tail idle CUs with dV blocks.
__global__ __launch_bounds__(256)
void k5_all(const __bf16* __restrict__ P, const __bf16* __restrict__ RsHpT,
            const __bf16* __restrict__ HpT, const __bf16* __restrict__ XT,
            const __bf16* __restrict__ r_h, const __bf16* __restrict__ ht_h,
            const __bf16* __restrict__ h_h, const float* __restrict__ proj,
            float* __restrict__ dout, float scale)
{
  const __bf16* Ap; int amode; const __bf16* Bp; const float* projA;
  float* out; int N; int m0i, n0i, zi;
  int b = blockIdx.x;
  if (b < 768) {
    int job = b >> 8, wb = b & 255;
    m0i = wb & 3; n0i = (wb >> 2) & 3; zi = wb >> 4;
    N = 512;
    out = dout + O_DW0 + (size_t)job * 262144;
    if (job == 0)      { Ap = P + 3 * THW; amode = 0; Bp = RsHpT; projA = proj; }
    else if (job == 1) { Ap = nullptr;     amode = 1; Bp = HpT;   projA = proj + 2 * 32768; }
    else               { Ap = P + 1 * THW; amode = 0; Bp = HpT;   projA = proj; }
  } else {
    int b2 = b - 768; int job = b2 >> 6, wb = b2 & 63;
    m0i = wb & 3; n0i = 0; zi = wb >> 2;
    N = 128;
    out = dout + O_DV0 + (size_t)job * 65536;
    if (job == 0)      { Ap = P + 2 * THW; amode = 0; Bp = XT; projA = proj; }
    else if (job == 1) { Ap = nullptr;     amode = 1; Bp = XT; projA = proj + 3 * 32768; }
    else               { Ap = P + 0 * THW; amode = 0; Bp = XT; projA = proj; }
  }
  const int m0 = m0i * 128;
  const int n0 = n0i * 128;
  const int klen = 1024;
  const int tid = threadIdx.x, lane = tid & 63, wv = tid >> 6, q = lane >> 4;
  const int wm = (wv & 1) * 64, wn = (wv >> 1) * 64;
  __shared__ __align__(16) __bf16 Al[128 * 72];
  __shared__ __align__(16) __bf16 Bl[128 * 72];
  f32x4 acc[4][4] = {};
  const int iters = klen >> 6;
  for (int kt = 0; kt < iters; ++kt) {
    const int kk0 = zi * klen + kt * 64;
    __syncthreads();
    #pragma unroll
    for (int e = 0; e < 8; ++e) {
      int idx = tid + e * 256;              // 0..2047
      int row = idx >> 4, c4 = (idx & 15) * 4;
      bf16x4 bv = *reinterpret_cast<const bf16x4*>(&Bp[(size_t)(n0 + row) * TBc + kk0 + c4]);
      *reinterpret_cast<bf16x4*>(&Bl[row * 72 + c4]) = bv;
    }
    if (amode == 0) {
      #pragma unroll
      for (int e = 0; e < 8; ++e) {
        int idx = tid + e * 256;
        int row = idx >> 4, c4 = (idx & 15) * 4;
        bf16x4 av = *reinterpret_cast<const bf16x4*>(&Ap[(size_t)(m0 + row) * TBc + kk0 + c4]);
        *reinterpret_cast<bf16x4*>(&Al[row * 72 + c4]) = av;
      }
    } else {
      #pragma unroll
      for (int e = 0; e < 8; ++e) {
        int idx = tid + e * 256;
        int kk = idx >> 5;                  // 0..63 local k row
        int m4 = (idx & 31) * 4;
        int kg = kk0 + kk;
        int tt = kg >> 6;
        bf16x4 hs = *reinterpret_cast<const bf16x4*>(&ht_h[(size_t)kg * 512 + m0 + m4]);
        bf16x4 rv = *reinterpret_cast<const bf16x4*>(&r_h[(size_t)kg * 512 + m0 + m4]);
        float4 pv = *reinterpret_cast<const float4*>(&projA[(size_t)(kg & 63) * 512 + m0 + m4]);
        float pvv[4] = {pv.x, pv.y, pv.z, pv.w};
        float hpf[4] = {0.f, 0.f, 0.f, 0.f};
        if (tt != 1) {
          int kr = (tt == 0) ? (16320 + (kg & 63)) : (kg - 128);
          bf16x4 hp = *reinterpret_cast<const bf16x4*>(&h_h[(size_t)kr * 512 + m0 + m4]);
          #pragma unroll
          for (int j = 0; j < 4; ++j) hpf[j] = (float)hp[j];
        }
        #pragma unroll
        for (int j = 0; j < 4; ++j) {
          float r = (float)rv[j];
          float zg = (hpf[j] - (float)hs[j]) * r * (1.f - r) * pvv[j];
          Al[(m4 + j) * 72 + kk] = (__bf16)zg;
        }
      }
    }
    __syncthreads();
    #pragma unroll
    for (int ks = 0; ks < 2; ++ks) {
      bf16x8 af[4], bfv[4];
      #pragma unroll
      for (int mi = 0; mi < 4; ++mi)
        af[mi] = *reinterpret_cast<const bf16x8*>(&Al[(wm + mi * 16 + (lane & 15)) * 72 + ks * 32 + q * 8]);
      #pragma unroll
      for (int ni = 0; ni < 4; ++ni)
        bfv[ni] = *reinterpret_cast<const bf16x8*>(&Bl[(wn + ni * 16 + (lane & 15)) * 72 + ks * 32 + q * 8]);
      #pragma unroll
      for (int mi = 0; mi < 4; ++mi)
        #pragma unroll
        for (int ni = 0; ni < 4; ++ni)
          acc[mi][ni] = __builtin_amdgcn_mfma_f32_16x16x32_bf16(af[mi], bfv[ni], acc[mi][ni], 0, 0, 0);
    }
  }
  #pragma unroll
  for (int mi = 0; mi < 4; ++mi) {
    const int m = m0 + wm + mi * 16 + q * 4;
    #pragma unroll
    for (int ni = 0; ni < 4; ++ni) {
      const int n = n0 + wn + ni * 16 + (lane & 15);
      #pragma unroll
      for (int i = 0; i < 4; ++i)
        atomicAdd(&out[(size_t)(m + i) * N + n], acc[mi][ni][i] * scale);
    }
  }
}

// =========================== db kernels ===========================
// merged: y=0 -> P-plane 2 (HV) into db[0..511]; y=1 -> P-plane 0 (AV) into db[1024..1535]
__global__ void k_dbP(const __bf16* __restrict__ P, float* __restrict__ db)
{
  const size_t plane = (blockIdx.y == 0) ? 2 : 0;
  const int dbo = (blockIdx.y == 0) ? 0 : 1024;
  const __bf16* row = P + plane * THW + (size_t)blockIdx.x * TBc;
  float sv = 0.f;
  for (int i = threadIdx.x; i < TBc; i += 256) sv += (float)row[i];
  for (int off = 32; off; off >>= 1) sv += __shfl_xor(sv, off, 64);
  __shared__ float red[4];
  if ((threadIdx.x & 63) == 0) red[threadIdx.x >> 6] = sv;
  __syncthreads();
  if (threadIdx.x == 0)
    atomicAdd(&db[dbo + blockIdx.x], (red[0] + red[1] + red[2] + red[3]) * (1.f / 64.f));
}

__global__ void k_dbzg(const __bf16* __restrict__ r_h, const __bf16* __restrict__ ht_h,
                       const __bf16* __restrict__ h_h, const float* __restrict__ proj,
                       float* __restrict__ db)
{
  const int hb = blockIdx.x * 64;
  const int col = hb + (threadIdx.x & 63);
  const int part = threadIdx.x >> 6;
  const int kb = blockIdx.y * 1024;
  float sum = 0.f;
  for (int k = kb + part; k < kb + 1024; k += 4) {
    float hs = (float)ht_h[(size_t)k * 512 + col];
    float r  = (float)r_h[(size_t)k * 512 + col];
    float hp = hprev_at(h_h, k, col);
    float pv = proj[3 * 32768 + (size_t)(k & 63) * 512 + col];
    sum += (hp - hs) * r * (1.f - r) * pv;
  }
  __shared__ float sred[4][64];
  sred[part][threadIdx.x & 63] = sum;
  __syncthreads();
  if (threadIdx.x < 64)
    atomicAdd(&db[512 + hb + threadIdx.x],
              (sred[0][threadIdx.x] + sred[1][threadIdx.x] +
               sred[2][threadIdx.x] + sred[3][threadIdx.x]) * (1.f / 64.f));
}

// =========================== K6: norm + clip (grads live in d_out) ===========================
__global__ void k6a_sumsq(const float* __restrict__ dout, const float* __restrict__ db,
                          float* __restrict__ slots)
{
  const int yy = blockIdx.y;
  const float* src; int count;
  if (yy < 3)      { src = dout + O_DW0 + (size_t)yy * 262144; count = 262144; }
  else if (yy < 6) { src = dout + O_DV0 + (size_t)(yy - 3) * 65536; count = 65536; }
  else             { src = db + (size_t)(yy - 6) * 512; count = 512; }
  int start = blockIdx.x * 4096;
  if (start >= count) return;
  int end = min(start + 4096, count);
  float sp = 0.f;
  for (int i = start + threadIdx.x; i < end; i += 256) { float v = src[i]; sp += v * v; }
  for (int off = 32; off; off >>= 1) sp += __shfl_xor(sp, off, 64);
  __shared__ float red[4];
  if ((threadIdx.x & 63) == 0) red[threadIdx.x >> 6] = sp;
  __syncthreads();
  if (threadIdx.x == 0) atomicAdd(&slots[yy], red[0] + red[1] + red[2] + red[3]);
}

__global__ void k6b_write(const float* __restrict__ db,
                          const float* __restrict__ slots, float* __restrict__ dout)
{
  const int yy = blockIdx.y;
  const float* src; int count; size_t oo;
  if (yy < 3)      { oo = O_DW0 + (size_t)yy * 262144; src = dout + oo; count = 262144; }
  else if (yy < 6) { oo = O_DV0 + (size_t)(yy - 3) * 65536; src = dout + oo; count = 65536; }
  else             { oo = O_DB0 + (size_t)(yy - 6) * 512; src = db + (size_t)(yy - 6) * 512; count = 512; }
  int start = blockIdx.x * 4096;
  if (start >= count) return;
  int end = min(start + 4096, count);
  float inv = 1.f / sqrtf(slots[yy]);
  for (int i = start + threadIdx.x; i < end; i += 256) {
    float v = src[i] * inv;
    dout[oo + i] = fminf(fmaxf(v, -5.f), 5.f);
  }
}

// =========================== launch ===========================
extern "C" void kernel_launch(void* const* d_in, const int* in_sizes, int n_in,
                              void* d_out, int out_size, void* d_ws, size_t ws_size,
                              hipStream_t stream)
{
  const float* x     = (const float*)d_in[0];
  const int*   y     = (const int*)d_in[1];
  const float* W1w   = (const float*)d_in[2];
  const float* V1w   = (const float*)d_in[3];
  const float* V1b   = (const float*)d_in[4];
  const float* W2w   = (const float*)d_in[5];
  const float* W2b   = (const float*)d_in[6];
  const float* V2w   = (const float*)d_in[7];
  const float* W3w   = (const float*)d_in[8];
  const float* W3b   = (const float*)d_in[9];
  const float* V3w   = (const float*)d_in[10];
  const float* Woutw = (const float*)d_in[11];
  const float* Woutb = (const float*)d_in[12];
  const float* BW1   = (const float*)d_in[13];
  const float* BV1   = (const float*)d_in[14];
  const float* BW2   = (const float*)d_in[15];
  const float* BV2   = (const float*)d_in[16];
  const float* BW3   = (const float*)d_in[17];
  const float* BV3   = (const float*)d_in[18];
  float* dout = (float*)d_out;
  char* ws = (char*)d_ws;

  if (ws_size < W_NEED) { ksent<<<1, 1, 0, stream>>>(dout, (float)ws_size); return; }

  float*  slots = (float*)(ws + W_SLOT);
  float*  dbr   = (float*)(ws + W_DB);
  int*    flg   = (int*)(ws + W_FLG);
  float*  errw  = (float*)(ws + W_ERRW);
  float*  proj  = (float*)(ws + W_PROJ);
  __bf16* W1b   = (__bf16*)(ws + W_W1B);
  float*  hx    = (float*)(ws + W_HX);
  float*  hrx   = (float*)(ws + W_HRX);
  __bf16* XT    = (__bf16*)(ws + W_XT);
  __bf16* r_h   = (__bf16*)(ws + W_HIST);
  __bf16* z_h   = (__bf16*)(ws + W_HIST + 16777216);
  __bf16* ht_h  = (__bf16*)(ws + W_HIST + 33554432);
  __bf16* h_h   = (__bf16*)(ws + W_HIST + 50331648);
  char*   PB    = ws + W_PB;

  // xV fp32 (dead after k2) aliases P/HpT/RsHpT (live after k2)
  float* xv1 = (float*)PB;
  float* xv2 = (float*)(PB + 33554432);
  float* xv3 = (float*)(PB + 67108864);
  __bf16* P     = (__bf16*)PB;                     // 4 x [512][TB] bf16 = 67.1 MB
  __bf16* HpT   = (__bf16*)(PB + 67108864);
  __bf16* RsHpT = (__bf16*)(PB + 83886080);

  kzero<<<16, 256, 0, stream>>>((float*)ws, 4096);                  // slots+dbr+flags
  kzero<<<3840, 256, 0, stream>>>(dout + O_DW0, 983040);            // grad accumulators
  k0_cast<<<1024, 256, 0, stream>>>(W1w, W1b, 262144);
  k1_xv<<<dim3(24, 256), 256, 0, stream>>>(x, V1w, V2w, V3w, V1b, W2b, W3b, xv1, xv2, xv3);
  e0_xt<<<256, 256, 0, stream>>>(x, XT);
  k2_recur<<<64, 256, 0, stream>>>(W1w, W2w, W3w, xv1, xv2, xv3,
                                   r_h, z_h, ht_h, h_h, hx, hrx, flg, dout);
  k3a_soft<<<64, 64, 0, stream>>>(Woutw, Woutb, y, dout, errw);
  k3b_proj<<<dim3(8, 6), 256, 0, stream>>>(errw, BW1, BV1, BW2, BV2, BW3, BV3, proj);
  e1t<<<dim3(8, 256), 256, 0, stream>>>(r_h, h_h, HpT, RsHpT);
  k_dbzg<<<dim3(8, 16), 256, 0, stream>>>(r_h, ht_h, h_h, proj, dbr);   // db1

  k4_pgemm<<<dim3(128, 4, 4), 256, 0, stream>>>(z_h, ht_h, r_h, h_h, proj, W1b, P);
  const float sc = 1.f / 64.f;
  // dW0/dW1/dW2 + dV0/dV1/dV2 in one 960-block launch
  k5_all<<<960, 256, 0, stream>>>(P, RsHpT, HpT, XT, r_h, ht_h, h_h, proj, dout, sc);
  k_dbP<<<dim3(512, 2), 256, 0, stream>>>(P, dbr);             // db0 (HV) + db2 (AV)
  k6a_sumsq<<<dim3(64, 9), 256, 0, stream>>>(dout, dbr, slots);
  k6b_write<<<dim3(64, 9), 256, 0, stream>>>(dbr, slots, dout);
}

// Round 7
// 2371.660 us; speedup vs baseline: 3.2967x; 1.0890x over previous
//
#include <hip/hip_runtime.h>
#include <hip/hip_bf16.h>

#define DI __device__ __forceinline__

typedef __bf16 bf16x8 __attribute__((ext_vector_type(8)));
typedef __bf16 bf16x4 __attribute__((ext_vector_type(4)));
typedef __bf16 bf16x2 __attribute__((ext_vector_type(2)));
typedef float  f32x4  __attribute__((ext_vector_type(4)));
typedef unsigned long long ull;

static constexpr int Bc = 64, Tc = 256, Ic = 128, Hc = 512, Oc = 64;
static constexpr int TBc = Tc * Bc;                 // 16384
static constexpr size_t THW = (size_t)TBc * Hc;     // 8388608 elems

// ---------- d_out offsets (floats) ----------
static constexpr size_t O_OUT = 0;
static constexpr size_t O_HT  = 4096;
static constexpr size_t O_DW0 = 36864;
static constexpr size_t O_DV0 = 823296;
static constexpr size_t O_DB0 = 1019904;
static constexpr size_t O_ERR = 1021440;

// ---------- ws offsets (bytes) ----------
static constexpr size_t W_SLOT = 1024;     // 9 f32
static constexpr size_t W_DB   = 2048;     // db_raw [3][512] f32 -> ends 8192
static constexpr size_t W_FLG  = 8192;     // barrier epoch flags: 64 slots x 128B -> ends 16384
static constexpr size_t W_ERRW = 16384;    // error [64][64] f32
static constexpr size_t W_PROJ = 32768;    // proj [6][64][512] f32 -> ends 819200
static constexpr size_t W_W1B  = 819200;   // W1 bf16 [512][512] -> ends 1343488
static constexpr size_t W_HX   = 1343488;  // h exchange fp32 [4][8192] (128 KB)
static constexpr size_t W_HRX  = 1474560;  // hr exchange fp32 [4][8192] -> ends 1605632
static constexpr size_t W_XT   = 1605632;  // x^T bf16 [128][TB] -> ends 5799936
static constexpr size_t W_HIST = 5799936;  // r,z,ht,h bf16 [TB][512] each -> ends 72908800
static constexpr size_t W_PB   = 72908800; // xV fp32 (100.6MB) / later P + HpT + RsHpT
static constexpr size_t W_NEED = W_PB + 100663296;   // 173572096

// =========================== helpers ===========================

DI void st32_agent(float* p, float v) {
  __hip_atomic_store((unsigned int*)p, __float_as_uint(v),
                     __ATOMIC_RELAXED, __HIP_MEMORY_SCOPE_AGENT);
}
DI ull ld64_agent(const void* p) {
  return __hip_atomic_load((ull*)p, __ATOMIC_RELAXED, __HIP_MEMORY_SCOPE_AGENT);
}

// Fence-free group barrier via distributed epoch flags. Each wg STORES the
// epoch to its own 128B-strided slot (no RMW); wave 0 polls all 16 slots with
// 16 parallel lanes. The leading __syncthreads() emits s_waitcnt vmcnt(0) per
// wave, draining the agent-scope exchange stores before the flag store.
DI void group_barrier(int* flags_g, int myslot, int bar, bool& dead) {
  __syncthreads();
  if (threadIdx.x == 0)
    __hip_atomic_store(&flags_g[myslot * 32], bar,
                       __ATOMIC_RELAXED, __HIP_MEMORY_SCOPE_AGENT);
  if (threadIdx.x < 64 && !dead) {
    const int l = threadIdx.x;
    int spins = 0;
    for (;;) {
      int v = bar;
      if (l < 16)
        v = __hip_atomic_load(&flags_g[l * 32],
                              __ATOMIC_RELAXED, __HIP_MEMORY_SCOPE_AGENT);
      if (__all(v >= bar)) break;
      __builtin_amdgcn_s_sleep(1);
      if (++spins > 4000000) { dead = true; break; }   // never hang the bench
    }
  }
  __syncthreads();
}

// hiddens[t-1] with python-negative-index quirk; k = t*64+b
DI float hprev_at(const __bf16* __restrict__ h_h, int k, int col) {
  int t = k >> 6;
  if (t == 1) return 0.f;
  int row = (t == 0) ? (16320 + (k & 63)) : (k - 128);
  return (float)h_h[(size_t)row * 512 + col];
}

// =========================== tiny kernels ===========================

__global__ void kzero(float* __restrict__ p, int n) {
  int i = blockIdx.x * 256 + threadIdx.x;
  if (i < n) p[i] = 0.f;
}
__global__ void ksent(float* p, float v) { p[0] = v; }

// =========================== K1: xV = x@V^T + bias (fp32) ===========================
__global__ __launch_bounds__(256)
void k1_xv(const float* __restrict__ x, const float* __restrict__ V1w,
           const float* __restrict__ V2w, const float* __restrict__ V3w,
           const float* __restrict__ V1b, const float* __restrict__ W2b,
           const float* __restrict__ W3b,
           float* __restrict__ xv1f, float* __restrict__ xv2f, float* __restrict__ xv3f)
{
  const int cb = blockIdx.x, t = blockIdx.y;
  const int g = cb >> 3, jblk = cb & 7;
  const float* Vg   = (g == 0) ? V1w : (g == 1) ? V2w : V3w;
  const float* bias = (g == 0) ? V1b : (g == 1) ? W2b : W3b;
  float* of = (g == 0) ? xv1f : (g == 1) ? xv2f : xv3f;
  __shared__ float As[64 * 69];
  __shared__ float Bs[64 * 69];
  const int tid = threadIdx.x;
  float acc[4][4] = {};
  const int m0 = (tid & 15) * 4, j0 = (tid >> 4) * 4;
  for (int kc = 0; kc < 2; ++kc) {
    __syncthreads();
    #pragma unroll
    for (int e = 0; e < 4; ++e) {
      int idx = tid + e * 256;            // 0..1023
      int row = idx >> 4, c4 = (idx & 15) * 4;
      float4 v = *reinterpret_cast<const float4*>(&x[((size_t)row * 256 + t) * 128 + kc * 64 + c4]);
      As[row * 69 + c4 + 0] = v.x; As[row * 69 + c4 + 1] = v.y;
      As[row * 69 + c4 + 2] = v.z; As[row * 69 + c4 + 3] = v.w;
      float4 w = *reinterpret_cast<const float4*>(&Vg[(size_t)(jblk * 64 + row) * 128 + kc * 64 + c4]);
      Bs[row * 69 + c4 + 0] = w.x; Bs[row * 69 + c4 + 1] = w.y;
      Bs[row * 69 + c4 + 2] = w.z; Bs[row * 69 + c4 + 3] = w.w;
    }
    __syncthreads();
    for (int i = 0; i < 64; ++i) {
      float a[4], b[4];
      #pragma unroll
      for (int u = 0; u < 4; ++u) a[u] = As[(m0 + u) * 69 + i];
      #pragma unroll
      for (int u = 0; u < 4; ++u) b[u] = Bs[(j0 + u) * 69 + i];
      #pragma unroll
      for (int mi = 0; mi < 4; ++mi)
        #pragma unroll
        for (int ji = 0; ji < 4; ++ji) acc[mi][ji] += a[mi] * b[ji];
    }
  }
  #pragma unroll
  for (int ji = 0; ji < 4; ++ji) {
    int jg = jblk * 64 + j0 + ji;
    float bv = bias[jg];
    #pragma unroll
    for (int mi = 0; mi < 4; ++mi) {
      int b = m0 + mi;
      of[((size_t)t * 64 + b) * 512 + jg] = acc[mi][ji] + bv;
    }
  }
}

// =========================== K2 mega-kernel =================================
// blocks 0..63: persistent GRU recurrence (4 groups x 16 col-wgs).
// blocks 64..319: e0_xt (X^T bf16 [128][TB]) -- independent, runs on idle CUs.
// blocks 320..351: W1 fp32->bf16 cast (consumed by k4, after k2).
// blocks 352..415: zero grad accumulators in dout (consumed by k5, after k2).
// Aux roles have no dependency on the recurrence: inputs ready before launch,
// outputs consumed after the kernel -- no added synchronization.
//
// Recurrence: 4 waves/wg = 2 col-tiles x 2 k-halves. Both operands split
// 2-WAY bf16 (Ootomo 3-term MFMA; dropped terms ~2^-16 relative, ~2e-5 abs
// per pre-activation -- absmax is pinned by bf16 history storage at 2^-11).
// h exchanged fp32; exchange layout == LDS fragment layout (identity):
// lane-consecutive 8B loads, conflict-free 4B-stride ds_writes. pbuf lane
// stride 9 (conflict-free). History stores after the flag (off drain path).
__global__ __launch_bounds__(256, 1)
void k2_recur(const float* __restrict__ W1w, const float* __restrict__ W2w,
              const float* __restrict__ W3w,
              const float* __restrict__ xv1, const float* __restrict__ xv2,
              const float* __restrict__ xv3,
              __bf16* __restrict__ r_h, __bf16* __restrict__ z_h,
              __bf16* __restrict__ ht_h, __bf16* __restrict__ h_h,
              float* __restrict__ hx, float* __restrict__ hrx,
              int* __restrict__ flags, float* __restrict__ dout,
              const float* __restrict__ x, __bf16* __restrict__ XT,
              __bf16* __restrict__ W1b)
{
  __shared__ __align__(16) char smem[37376];
  const int tid = threadIdx.x;
  const int bid = blockIdx.x;

  if (bid >= 64) {
    if (bid < 320) {
      // ---- e0_xt: X^T bf16 [128][TB] ----
      const int t = bid - 64;
      __bf16* xs = (__bf16*)smem;          // [64][132]
      #pragma unroll
      for (int e = 0; e < 8; ++e) {
        int idx = tid + e * 256;           // 0..2047
        int b = idx >> 5, c4 = (idx & 31) * 4;
        float4 v = *reinterpret_cast<const float4*>(&x[((size_t)b * 256 + t) * 128 + c4]);
        xs[b * 132 + c4 + 0] = (__bf16)v.x; xs[b * 132 + c4 + 1] = (__bf16)v.y;
        xs[b * 132 + c4 + 2] = (__bf16)v.z; xs[b * 132 + c4 + 3] = (__bf16)v.w;
      }
      __syncthreads();
      #pragma unroll
      for (int e = 0; e < 8; ++e) {
        int idx = tid + e * 256;
        int i = idx >> 4, b4 = (idx & 15) * 4;
        __bf16* d = &XT[(size_t)i * TBc + t * 64 + b4];
        d[0] = xs[(b4 + 0) * 132 + i];
        d[1] = xs[(b4 + 1) * 132 + i];
        d[2] = xs[(b4 + 2) * 132 + i];
        d[3] = xs[(b4 + 3) * 132 + i];
      }
    } else if (bid < 352) {
      // ---- W1 fp32 -> bf16 cast (262144 elems, 32 wgs grid-stride) ----
      for (int i = (bid - 320) * 256 + tid; i < 262144; i += 32 * 256)
        W1b[i] = (__bf16)W1w[i];
    } else {
      // ---- zero grad accumulators (983040 floats, 64 wgs grid-stride) ----
      float* p = dout + O_DW0;
      for (int i = (bid - 352) * 256 + tid; i < 983040; i += 64 * 256)
        p[i] = 0.f;
    }
    return;
  }

  // ---------------- recurrence ----------------
  const int g  = bid >> 4;             // batch group 0..3
  const int cw = bid & 15;             // col-wg 0..15
  const int lane = tid & 63, wv = tid >> 6;
  const int kh = wv & 1;               // k-half
  const int ct = wv >> 1;              // col-tile
  const int q  = lane >> 4;
  const int colc = cw * 32 + ct * 16 + (lane & 15);
  const bool owner = (kh == 0);

  __bf16* c0  = (__bf16*)smem;                 // h comp0 frags [16kk][64lane][8]
  __bf16* c1  = (__bf16*)(smem + 16384);       // h comp1 frags
  float*  pbuf = (float*)(smem + 32768);       // cross-wave partials, 9-stride

  // weight fragments, 2-way split: lane n=colc, k = (kh*8+kk2)*32 + q*8 + j
  bf16x8 w1c[2][8], w2c[2][8], w3c[2][8];
  #pragma unroll
  for (int kk2 = 0; kk2 < 8; ++kk2) {
    const int kb = (kh * 8 + kk2) * 32 + q * 8;
    #pragma unroll
    for (int j = 0; j < 8; ++j) {
      float w = W1w[(size_t)colc * 512 + kb + j];
      __bf16 a = (__bf16)w;
      w1c[0][kk2][j] = a; w1c[1][kk2][j] = (__bf16)(w - (float)a);
      w = W2w[(size_t)colc * 512 + kb + j];
      a = (__bf16)w;
      w2c[0][kk2][j] = a; w2c[1][kk2][j] = (__bf16)(w - (float)a);
      w = W3w[(size_t)colc * 512 + kb + j];
      a = (__bf16)w;
      w3c[0][kk2][j] = a; w3c[1][kk2][j] = (__bf16)(w - (float)a);
    }
  }
  for (int i = tid; i < 8192; i += 256) {
    c0[i] = (__bf16)0.f; c1[i] = (__bf16)0.f;
  }
  __syncthreads();

  float hreg[4] = {0.f, 0.f, 0.f, 0.f};
  float* hx_g  = hx  + g * 8192;
  float* hrx_g = hrx + g * 8192;
  int* flags_g = flags + g * 16 * 32;
  // frag index for state element (m=q*4+i, c=colc)
  const int fragbase = (colc >> 5) * 512 + (((colc >> 3) & 3) * 16 + q * 4) * 8 + (colc & 7);
  const int pb = (ct * 64 + lane) * 9;

  // coalesced exchange reload: lane-consecutive ull loads, identity map to
  // the c0/c1 fragment layout (LDS byte offset = 4 * ull index).
  auto stage = [&](const float* __restrict__ srcf) {
    const ull* src = reinterpret_cast<const ull*>(srcf);
    ull u[16];
    #pragma unroll
    for (int j = 0; j < 16; ++j) u[j] = ld64_agent(src + j * 256 + tid);
    #pragma unroll
    for (int j = 0; j < 16; ++j) {
      float f0 = __uint_as_float((unsigned int)u[j]);
      float f1 = __uint_as_float((unsigned int)(u[j] >> 32));
      __bf16 a0 = (__bf16)f0; __bf16 b0 = (__bf16)(f0 - (float)a0);
      __bf16 a1 = (__bf16)f1; __bf16 b1 = (__bf16)(f1 - (float)a1);
      int o = (j * 256 + tid) * 2;
      bf16x2 v0; v0[0] = a0; v0[1] = a1;
      bf16x2 v1; v1[0] = b0; v1[1] = b1;
      *reinterpret_cast<bf16x2*>(&c0[o]) = v0;
      *reinterpret_cast<bf16x2*>(&c1[o]) = v1;
    }
  };

  bool dead = false;
  int bar = 0;
  #pragma unroll 1
  for (int t = 0; t < Tc; ++t) {
    const size_t rowb = ((size_t)t * 64 + g * 16 + q * 4) * 512 + colc;
    float xv1v[4], xv2v[4], xv3v[4];
    if (owner) {
      #pragma unroll
      for (int i = 0; i < 4; ++i) {
        size_t o = rowb + (size_t)i * 512;
        xv1v[i] = xv1[o]; xv2v[i] = xv2[o]; xv3v[i] = xv3[o];
      }
    }
    // ---- phase 1: z, r gates (2-way split, 3 terms each) ----
    f32x4 a2 = {0.f,0.f,0.f,0.f}, a3 = {0.f,0.f,0.f,0.f};
    #pragma unroll
    for (int kk2 = 0; kk2 < 8; ++kk2) {
      const int idx = (kh * 8 + kk2) * 512 + lane * 8;
      bf16x8 h0 = *reinterpret_cast<const bf16x8*>(&c0[idx]);
      bf16x8 h1 = *reinterpret_cast<const bf16x8*>(&c1[idx]);
      a2 = __builtin_amdgcn_mfma_f32_16x16x32_bf16(h0, w2c[0][kk2], a2, 0, 0, 0);
      a2 = __builtin_amdgcn_mfma_f32_16x16x32_bf16(h1, w2c[0][kk2], a2, 0, 0, 0);
      a2 = __builtin_amdgcn_mfma_f32_16x16x32_bf16(h0, w2c[1][kk2], a2, 0, 0, 0);
      a3 = __builtin_amdgcn_mfma_f32_16x16x32_bf16(h0, w3c[0][kk2], a3, 0, 0, 0);
      a3 = __builtin_amdgcn_mfma_f32_16x16x32_bf16(h1, w3c[0][kk2], a3, 0, 0, 0);
      a3 = __builtin_amdgcn_mfma_f32_16x16x32_bf16(h0, w3c[1][kk2], a3, 0, 0, 0);
    }
    if (!owner) {
      #pragma unroll
      for (int i = 0; i < 4; ++i) { pbuf[pb + i] = a2[i]; pbuf[pb + 4 + i] = a3[i]; }
    }
    __syncthreads();
    float zz[4], rr4[4];
    if (owner) {
      // exchange stores only (they gate the barrier drain)
      #pragma unroll
      for (int i = 0; i < 4; ++i) {
        float s2 = a2[i] + pbuf[pb + i]     + xv2v[i];
        float s3 = a3[i] + pbuf[pb + 4 + i] + xv3v[i];
        zz[i]  = 1.f / (1.f + expf(-s2));
        rr4[i] = 1.f / (1.f + expf(-s3));
        st32_agent(&hrx_g[fragbase + i * 8], hreg[i] * rr4[i]);
      }
    }
    ++bar; group_barrier(flags_g, cw, bar, dead);
    // history stores AFTER the flag: their drain overlaps the stage loads
    if (owner) {
      #pragma unroll
      for (int i = 0; i < 4; ++i) {
        z_h[rowb + (size_t)i * 512] = (__bf16)zz[i];
        r_h[rowb + (size_t)i * 512] = (__bf16)rr4[i];
      }
    }
    stage(hrx_g);
    __syncthreads();
    // ---- phase 2: candidate + update (2-way split, 3 terms) ----
    f32x4 a1 = {0.f,0.f,0.f,0.f};
    #pragma unroll
    for (int kk2 = 0; kk2 < 8; ++kk2) {
      const int idx = (kh * 8 + kk2) * 512 + lane * 8;
      bf16x8 h0 = *reinterpret_cast<const bf16x8*>(&c0[idx]);
      bf16x8 h1 = *reinterpret_cast<const bf16x8*>(&c1[idx]);
      a1 = __builtin_amdgcn_mfma_f32_16x16x32_bf16(h0, w1c[0][kk2], a1, 0, 0, 0);
      a1 = __builtin_amdgcn_mfma_f32_16x16x32_bf16(h1, w1c[0][kk2], a1, 0, 0, 0);
      a1 = __builtin_amdgcn_mfma_f32_16x16x32_bf16(h0, w1c[1][kk2], a1, 0, 0, 0);
    }
    if (!owner) {
      #pragma unroll
      for (int i = 0; i < 4; ++i) pbuf[pb + i] = a1[i];
    }
    __syncthreads();
    float htv[4];
    if (owner) {
      #pragma unroll
      for (int i = 0; i < 4; ++i) {
        float pre = a1[i] + pbuf[pb + i] + xv1v[i];
        float ht = tanhf(pre);
        float hn = zz[i] * (hreg[i] - ht) + ht;
        htv[i] = ht;
        hreg[i] = hn;
        st32_agent(&hx_g[fragbase + i * 8], hn);
      }
    }
    ++bar; group_barrier(flags_g, cw, bar, dead);
    if (owner) {
      #pragma unroll
      for (int i = 0; i < 4; ++i) {
        ht_h[rowb + (size_t)i * 512] = (__bf16)htv[i];
        h_h[rowb + (size_t)i * 512]  = (__bf16)hreg[i];
      }
    }
    if (t + 1 < Tc) stage(hx_g);
    __syncthreads();
  }
  if (owner) {
    #pragma unroll
    for (int i = 0; i < 4; ++i) {
      int b = g * 16 + q * 4 + i;
      dout[O_HT + (size_t)b * 512 + colc] = hreg[i];
    }
  }
}

// =========================== K3a: logits/softmax/error ===========================
__global__ void k3a_soft(const float* __restrict__ Woutw, const float* __restrict__ Woutb,
                         const int* __restrict__ y, float* __restrict__ dout,
                         float* __restrict__ errw)
{
  const int b = blockIdx.x, o = threadIdx.x;
  const float* hrow = dout + O_HT + (size_t)b * 512;
  float sv = Woutb[o];
  for (int k = 0; k < 512; ++k) sv += hrow[k] * Woutw[(size_t)o * 512 + k];
  float mx = sv;
  for (int off = 32; off; off >>= 1) mx = fmaxf(mx, __shfl_xor(mx, off, 64));
  float e = expf(sv - mx);
  float sum = e;
  for (int off = 32; off; off >>= 1) sum += __shfl_xor(sum, off, 64);
  float outp = e / sum;
  float errv = outp - ((y[b] == o) ? 1.f : 0.f);
  dout[O_OUT + b * 64 + o] = outp;
  dout[O_ERR + b * 64 + o] = errv;
  errw[b * 64 + o] = errv;
}

// =========================== K3b: 6 DFA projections ===========================
__global__ __launch_bounds__(256)
void k3b_proj(const float* __restrict__ err,
              const float* b0, const float* b1, const float* b2,
              const float* b3, const float* b4, const float* b5,
              float* __restrict__ proj)
{
  const int p = blockIdx.y;
  const int hb = blockIdx.x * 64;
  const float* BX = (p==0)?b0:(p==1)?b1:(p==2)?b2:(p==3)?b3:(p==4)?b4:b5;
  __shared__ float es[64 * 64];
  __shared__ float bs[64 * 65];
  for (int i = threadIdx.x; i < 4096; i += 256) es[i] = err[i];
  for (int i = threadIdx.x; i < 4096; i += 256) {
    int o = i >> 6, hh = i & 63;
    bs[o * 65 + hh] = BX[(size_t)o * 512 + hb + hh];
  }
  __syncthreads();
  for (int e = 0; e < 16; ++e) {
    int idx = threadIdx.x + e * 256;
    int b = idx >> 6, hh = idx & 63;
    float s = 0.f;
    for (int o = 0; o < 64; ++o) s += es[b * 64 + o] * bs[o * 65 + hh];
    proj[(size_t)p * 32768 + b * 512 + hb + hh] = s;
  }
}

// =========================== E1T: HpT / RsHpT m-major [512][TB] ===========================
__global__ __launch_bounds__(256)
void e1t(const __bf16* __restrict__ r_h, const __bf16* __restrict__ h_h,
         __bf16* __restrict__ HpT, __bf16* __restrict__ RsHpT)
{
  const int t = blockIdx.y, hb = blockIdx.x * 64;
  const int tid = threadIdx.x;
  __shared__ __bf16 tr[64 * 68];
  float hpv[16], rv[16];
  #pragma unroll
  for (int e = 0; e < 16; ++e) {
    int idx = tid + e * 256;
    int b = idx >> 6, hl = idx & 63;
    hpv[e] = hprev_at(h_h, t * 64 + b, hb + hl);
    rv[e]  = (float)r_h[((size_t)t * 64 + b) * 512 + hb + hl];
  }
  for (int rnd = 0; rnd < 2; ++rnd) {
    __syncthreads();
    #pragma unroll
    for (int e = 0; e < 16; ++e) {
      int idx = tid + e * 256;
      int b = idx >> 6, hl = idx & 63;
      tr[b * 68 + hl] = (__bf16)(rnd == 0 ? hpv[e] : rv[e] * hpv[e]);
    }
    __syncthreads();
    __bf16* dst = (rnd == 0) ? HpT : RsHpT;
    #pragma unroll
    for (int e = 0; e < 16; ++e) {
      int idx = tid + e * 256;
      int hl2 = idx >> 6, b2 = idx & 63;
      dst[(size_t)(hb + hl2) * TBc + t * 64 + b2] = tr[b2 * 68 + hl2];
    }
  }
}

// =========================== K4: P = (G @ W1^T) * mul, G fused, m-major out ==========
__global__ __launch_bounds__(256)
void k4_pgemm(const __bf16* __restrict__ z_h, const __bf16* __restrict__ ht_h,
              const __bf16* __restrict__ r_h, const __bf16* __restrict__ h_h,
              const float* __restrict__ proj, const __bf16* __restrict__ W1b,
              __bf16* __restrict__ P)
{
  const int p = blockIdx.z;
  const int krow0 = blockIdx.x * 128;
  const int n0 = blockIdx.y * 128;
  const int pidx = (p == 0) ? 5 : (p == 1) ? 4 : (p == 2) ? 1 : 0;
  const float* pr = proj + (size_t)pidx * 32768;
  const int tid = threadIdx.x, lane = tid & 63, wv = tid >> 6, q = lane >> 4;
  const int wm = (wv & 1) * 64, wn = (wv >> 1) * 64;
  __shared__ __align__(16) __bf16 Al[128 * 40];
  __shared__ __align__(16) __bf16 Bl[128 * 40];
  f32x4 acc[4][4] = {};
  for (int kt = 0; kt < 16; ++kt) {
    const int h0 = kt * 32;
    __syncthreads();
    #pragma unroll
    for (int e = 0; e < 4; ++e) {
      int idx = tid + e * 256;                 // 0..1023
      int row = idx >> 3, h4 = (idx & 7) * 4;
      int kg = krow0 + row;
      bf16x4 zz = *reinterpret_cast<const bf16x4*>(&z_h[(size_t)kg * 512 + h0 + h4]);
      bf16x4 tt = *reinterpret_cast<const bf16x4*>(&ht_h[(size_t)kg * 512 + h0 + h4]);
      float4 pv = *reinterpret_cast<const float4*>(&pr[(size_t)(kg & 63) * 512 + h0 + h4]);
      float pvv[4] = {pv.x, pv.y, pv.z, pv.w};
      bf16x4 gv;
      #pragma unroll
      for (int j = 0; j < 4; ++j) {
        float sz = 1.f - (float)zz[j];
        float v = pvv[j] * sz;
        if (p < 2) { float h = (float)tt[j]; v *= (1.f - h * h); }
        gv[j] = (__bf16)v;
      }
      *reinterpret_cast<bf16x4*>(&Al[row * 40 + h4]) = gv;
      bf16x4 wv4 = *reinterpret_cast<const bf16x4*>(&W1b[(size_t)(n0 + row) * 512 + h0 + h4]);
      *reinterpret_cast<bf16x4*>(&Bl[row * 40 + h4]) = wv4;
    }
    __syncthreads();
    bf16x8 af[4], bfv[4];
    #pragma unroll
    for (int mi = 0; mi < 4; ++mi)
      af[mi] = *reinterpret_cast<const bf16x8*>(&Al[(wm + mi * 16 + (lane & 15)) * 40 + q * 8]);
    #pragma unroll
    for (int ni = 0; ni < 4; ++ni)
      bfv[ni] = *reinterpret_cast<const bf16x8*>(&Bl[(wn + ni * 16 + (lane & 15)) * 40 + q * 8]);
    #pragma unroll
    for (int mi = 0; mi < 4; ++mi)
      #pragma unroll
      for (int ni = 0; ni < 4; ++ni)
        acc[mi][ni] = __builtin_amdgcn_mfma_f32_16x16x32_bf16(af[mi], bfv[ni], acc[mi][ni], 0, 0, 0);
  }
  __bf16* Pp = P + (size_t)p * THW;
  #pragma unroll
  for (int mi = 0; mi < 4; ++mi) {
    const int kg = krow0 + wm + mi * 16 + q * 4;
    const int tt = kg >> 6;
    #pragma unroll
    for (int ni = 0; ni < 4; ++ni) {
      const int n = n0 + wn + ni * 16 + (lane & 15);
      union { __bf16 b[4]; uint2 u; } pk;
      #pragma unroll
      for (int i = 0; i < 4; ++i) {
        float mul;
        if (p < 2) {
          float r = (float)r_h[(size_t)(kg + i) * 512 + n];
          float hp = 0.f;
          if (tt != 1) {
            int kr = (tt == 0) ? (16320 + (kg & 63) + i) : (kg + i - 128);
            hp = (float)h_h[(size_t)kr * 512 + n];
          }
          mul = hp * r * (1.f - r);
        } else {
          float h = (float)ht_h[(size_t)(kg + i) * 512 + n];
          mul = 1.f - h * h;
        }
        pk.b[i] = (__bf16)(acc[mi][ni][i] * mul);
      }
      *reinterpret_cast<uint2*>(&Pp[(size_t)n * TBc + kg]) = pk.u;
    }
  }
}

// =========================== K5: merged TN grad GEMMs (6 jobs, 960 blocks) ==========
__global__ __launch_bounds__(256)
void k5_all(const __bf16* __restrict__ P, const __bf16* __restrict__ RsHpT,
            const __bf16* __restrict__ HpT, const __bf16* __restrict__ XT,
            const __bf16* __restrict__ r_h, const __bf16* __restrict__ ht_h,
            const __bf16* __restrict__ h_h, const float* __restrict__ proj,
            float* __restrict__ dout, float scale)
{
  const __bf16* Ap; int amode; const __bf16* Bp; const float* projA;
  float* out; int N; int m0i, n0i, zi;
  int b = blockIdx.x;
  if (b < 768) {
    int job = b >> 8, wb = b & 255;
    m0i = wb & 3; n0i = (wb >> 2) & 3; zi = wb >> 4;
    N = 512;
    out = dout + O_DW0 + (size_t)job * 262144;
    if (job == 0)      { Ap = P + 3 * THW; amode = 0; Bp = RsHpT; projA = proj; }
    else if (job == 1) { Ap = nullptr;     amode = 1; Bp = HpT;   projA = proj + 2 * 32768; }
    else               { Ap = P + 1 * THW; amode = 0; Bp = HpT;   projA = proj; }
  } else {
    int b2 = b - 768; int job = b2 >> 6, wb = b2 & 63;
    m0i = wb & 3; n0i = 0; zi = wb >> 2;
    N = 128;
    out = dout + O_DV0 + (size_t)job * 65536;
    if (job == 0)      { Ap = P + 2 * THW; amode = 0; Bp = XT; projA = proj; }
    else if (job == 1) { Ap = nullptr;     amode = 1; Bp = XT; projA = proj + 3 * 32768; }
    else               { Ap = P + 0 * THW; amode = 0; Bp = XT; projA = proj; }
  }
  const int m0 = m0i * 128;
  const int n0 = n0i * 128;
  const int klen = 1024;
  const int tid = threadIdx.x, lane = tid & 63, wv = tid >> 6, q = lane >> 4;
  const int wm = (wv & 1) * 64, wn = (wv >> 1) * 64;
  __shared__ __align__(16) __bf16 Al[128 * 72];
  __shared__ __align__(16) __bf16 Bl[128 * 72];
  f32x4 acc[4][4] = {};
  const int iters = klen >> 6;
  for (int kt = 0; kt < iters; ++kt) {
    const int kk0 = zi * klen + kt * 64;
    __syncthreads();
    #pragma unroll
    for (int e = 0; e < 8; ++e) {
      int idx = tid + e * 256;              // 0..2047
      int row = idx >> 4, c4 = (idx & 15) * 4;
      bf16x4 bv = *reinterpret_cast<const bf16x4*>(&Bp[(size_t)(n0 + row) * TBc + kk0 + c4]);
      *reinterpret_cast<bf16x4*>(&Bl[row * 72 + c4]) = bv;
    }
    if (amode == 0) {
      #pragma unroll
      for (int e = 0; e < 8; ++e) {
        int idx = tid + e * 256;
        int row = idx >> 4, c4 = (idx & 15) * 4;
        bf16x4 av = *reinterpret_cast<const bf16x4*>(&Ap[(size_t)(m0 + row) * TBc + kk0 + c4]);
        *reinterpret_cast<bf16x4*>(&Al[row * 72 + c4]) = av;
      }
    } else {
      #pragma unroll
      for (int e = 0; e < 8; ++e) {
        int idx = tid + e * 256;
        int kk = idx >> 5;                  // 0..63 local k row
        int m4 = (idx & 31) * 4;
        int kg = kk0 + kk;
        int tt = kg >> 6;
        bf16x4 hs = *reinterpret_cast<const bf16x4*>(&ht_h[(size_t)kg * 512 + m0 + m4]);
        bf16x4 rv = *reinterpret_cast<const bf16x4*>(&r_h[(size_t)kg * 512 + m0 + m4]);
        float4 pv = *reinterpret_cast<const float4*>(&projA[(size_t)(kg & 63) * 512 + m0 + m4]);
        float pvv[4] = {pv.x, pv.y, pv.z, pv.w};
        float hpf[4] = {0.f, 0.f, 0.f, 0.f};
        if (tt != 1) {
          int kr = (tt == 0) ? (16320 + (kg & 63)) : (kg - 128);
          bf16x4 hp = *reinterpret_cast<const bf16x4*>(&h_h[(size_t)kr * 512 + m0 + m4]);
          #pragma unroll
          for (int j = 0; j < 4; ++j) hpf[j] = (float)hp[j];
        }
        #pragma unroll
        for (int j = 0; j < 4; ++j) {
          float r = (float)rv[j];
          float zg = (hpf[j] - (float)hs[j]) * r * (1.f - r) * pvv[j];
          Al[(m4 + j) * 72 + kk] = (__bf16)zg;
        }
      }
    }
    __syncthreads();
    #pragma unroll
    for (int ks = 0; ks < 2; ++ks) {
      bf16x8 af[4], bfv[4];
      #pragma unroll
      for (int mi = 0; mi < 4; ++mi)
        af[mi] = *reinterpret_cast<const bf16x8*>(&Al[(wm + mi * 16 + (lane & 15)) * 72 + ks * 32 + q * 8]);
      #pragma unroll
      for (int ni = 0; ni < 4; ++ni)
        bfv[ni] = *reinterpret_cast<const bf16x8*>(&Bl[(wn + ni * 16 + (lane & 15)) * 72 + ks * 32 + q * 8]);
      #pragma unroll
      for (int mi = 0; mi < 4; ++mi)
        #pragma unroll
        for (int ni = 0; ni < 4; ++ni)
          acc[mi][ni] = __builtin_amdgcn_mfma_f32_16x16x32_bf16(af[mi], bfv[ni], acc[mi][ni], 0, 0, 0);
    }
  }
  #pragma unroll
  for (int mi = 0; mi < 4; ++mi) {
    const int m = m0 + wm + mi * 16 + q * 4;
    #pragma unroll
    for (int ni = 0; ni < 4; ++ni) {
      const int n = n0 + wn + ni * 16 + (lane & 15);
      #pragma unroll
      for (int i = 0; i < 4; ++i)
        atomicAdd(&out[(size_t)(m + i) * N + n], acc[mi][ni][i] * scale);
    }
  }
}

// =========================== db kernels ===========================
__global__ void k_dbP(const __bf16* __restrict__ P, float* __restrict__ db)
{
  const size_t plane = (blockIdx.y == 0) ? 2 : 0;
  const int dbo = (blockIdx.y == 0) ? 0 : 1024;
  const __bf16* row = P + plane * THW + (size_t)blockIdx.x * TBc;
  float sv = 0.f;
  for (int i = threadIdx.x; i < TBc; i += 256) sv += (float)row[i];
  for (int off = 32; off; off >>= 1) sv += __shfl_xor(sv, off, 64);
  __shared__ float red[4];
  if ((threadIdx.x & 63) == 0) red[threadIdx.x >> 6] = sv;
  __syncthreads();
  if (threadIdx.x == 0)
    atomicAdd(&db[dbo + blockIdx.x], (red[0] + red[1] + red[2] + red[3]) * (1.f / 64.f));
}

__global__ void k_dbzg(const __bf16* __restrict__ r_h, const __bf16* __restrict__ ht_h,
                       const __bf16* __restrict__ h_h, const float* __restrict__ proj,
                       float* __restrict__ db)
{
  const int hb = blockIdx.x * 64;
  const int col = hb + (threadIdx.x & 63);
  const int part = threadIdx.x >> 6;
  const int kb = blockIdx.y * 1024;
  float sum = 0.f;
  for (int k = kb + part; k < kb + 1024; k += 4) {
    float hs = (float)ht_h[(size_t)k * 512 + col];
    float r  = (float)r_h[(size_t)k * 512 + col];
    float hp = hprev_at(h_h, k, col);
    float pv = proj[3 * 32768 + (size_t)(k & 63) * 512 + col];
    sum += (hp - hs) * r * (1.f - r) * pv;
  }
  __shared__ float sred[4][64];
  sred[part][threadIdx.x & 63] = sum;
  __syncthreads();
  if (threadIdx.x < 64)
    atomicAdd(&db[512 + hb + threadIdx.x],
              (sred[0][threadIdx.x] + sred[1][threadIdx.x] +
               sred[2][threadIdx.x] + sred[3][threadIdx.x]) * (1.f / 64.f));
}

// =========================== K6: norm + clip (grads live in d_out) ===========================
__global__ void k6a_sumsq(const float* __restrict__ dout, const float* __restrict__ db,
                          float* __restrict__ slots)
{
  const int yy = blockIdx.y;
  const float* src; int count;
  if (yy < 3)      { src = dout + O_DW0 + (size_t)yy * 262144; count = 262144; }
  else if (yy < 6) { src = dout + O_DV0 + (size_t)(yy - 3) * 65536; count = 65536; }
  else             { src = db + (size_t)(yy - 6) * 512; count = 512; }
  int start = blockIdx.x * 4096;
  if (start >= count) return;
  int end = min(start + 4096, count);
  float sp = 0.f;
  for (int i = start + threadIdx.x; i < end; i += 256) { float v = src[i]; sp += v * v; }
  for (int off = 32; off; off >>= 1) sp += __shfl_xor(sp, off, 64);
  __shared__ float red[4];
  if ((threadIdx.x & 63) == 0) red[threadIdx.x >> 6] = sp;
  __syncthreads();
  if (threadIdx.x == 0) atomicAdd(&slots[yy], red[0] + red[1] + red[2] + red[3]);
}

__global__ void k6b_write(const float* __restrict__ db,
                          const float* __restrict__ slots, float* __restrict__ dout)
{
  const int yy = blockIdx.y;
  const float* src; int count; size_t oo;
  if (yy < 3)      { oo = O_DW0 + (size_t)yy * 262144; src = dout + oo; count = 262144; }
  else if (yy < 6) { oo = O_DV0 + (size_t)(yy - 3) * 65536; src = dout + oo; count = 65536; }
  else             { oo = O_DB0 + (size_t)(yy - 6) * 512; src = db + (size_t)(yy - 6) * 512; count = 512; }
  int start = blockIdx.x * 4096;
  if (start >= count) return;
  int end = min(start + 4096, count);
  float inv = 1.f / sqrtf(slots[yy]);
  for (int i = start + threadIdx.x; i < end; i += 256) {
    float v = src[i] * inv;
    dout[oo + i] = fminf(fmaxf(v, -5.f), 5.f);
  }
}

// =========================== launch ===========================
extern "C" void kernel_launch(void* const* d_in, const int* in_sizes, int n_in,
                              void* d_out, int out_size, void* d_ws, size_t ws_size,
                              hipStream_t stream)
{
  const float* x     = (const float*)d_in[0];
  const int*   y     = (const int*)d_in[1];
  const float* W1w   = (const float*)d_in[2];
  const float* V1w   = (const float*)d_in[3];
  const float* V1b   = (const float*)d_in[4];
  const float* W2w   = (const float*)d_in[5];
  const float* W2b   = (const float*)d_in[6];
  const float* V2w   = (const float*)d_in[7];
  const float* W3w   = (const float*)d_in[8];
  const float* W3b   = (const float*)d_in[9];
  const float* V3w   = (const float*)d_in[10];
  const float* Woutw = (const float*)d_in[11];
  const float* Woutb = (const float*)d_in[12];
  const float* BW1   = (const float*)d_in[13];
  const float* BV1   = (const float*)d_in[14];
  const float* BW2   = (const float*)d_in[15];
  const float* BV2   = (const float*)d_in[16];
  const float* BW3   = (const float*)d_in[17];
  const float* BV3   = (const float*)d_in[18];
  float* dout = (float*)d_out;
  char* ws = (char*)d_ws;

  if (ws_size < W_NEED) { ksent<<<1, 1, 0, stream>>>(dout, (float)ws_size); return; }

  float*  slots = (float*)(ws + W_SLOT);
  float*  dbr   = (float*)(ws + W_DB);
  int*    flg   = (int*)(ws + W_FLG);
  float*  errw  = (float*)(ws + W_ERRW);
  float*  proj  = (float*)(ws + W_PROJ);
  __bf16* W1b   = (__bf16*)(ws + W_W1B);
  float*  hx    = (float*)(ws + W_HX);
  float*  hrx   = (float*)(ws + W_HRX);
  __bf16* XT    = (__bf16*)(ws + W_XT);
  __bf16* r_h   = (__bf16*)(ws + W_HIST);
  __bf16* z_h   = (__bf16*)(ws + W_HIST + 16777216);
  __bf16* ht_h  = (__bf16*)(ws + W_HIST + 33554432);
  __bf16* h_h   = (__bf16*)(ws + W_HIST + 50331648);
  char*   PB    = ws + W_PB;

  // xV fp32 (dead after k2) aliases P/HpT/RsHpT (live after k2)
  float* xv1 = (float*)PB;
  float* xv2 = (float*)(PB + 33554432);
  float* xv3 = (float*)(PB + 67108864);
  __bf16* P     = (__bf16*)PB;                     // 4 x [512][TB] bf16 = 67.1 MB
  __bf16* HpT   = (__bf16*)(PB + 67108864);
  __bf16* RsHpT = (__bf16*)(PB + 83886080);

  kzero<<<16, 256, 0, stream>>>((float*)ws, 4096);                  // slots+dbr+flags
  k1_xv<<<dim3(24, 256), 256, 0, stream>>>(x, V1w, V2w, V3w, V1b, W2b, W3b, xv1, xv2, xv3);
  // mega kernel: recurrence (blocks 0..63) + e0_xt (64..319) + W1 cast
  // (320..351) + grad-accumulator zero (352..415) on otherwise-idle CUs
  k2_recur<<<416, 256, 0, stream>>>(W1w, W2w, W3w, xv1, xv2, xv3,
                                    r_h, z_h, ht_h, h_h, hx, hrx, flg, dout,
                                    x, XT, W1b);
  k3a_soft<<<64, 64, 0, stream>>>(Woutw, Woutb, y, dout, errw);
  k3b_proj<<<dim3(8, 6), 256, 0, stream>>>(errw, BW1, BV1, BW2, BV2, BW3, BV3, proj);
  e1t<<<dim3(8, 256), 256, 0, stream>>>(r_h, h_h, HpT, RsHpT);
  k_dbzg<<<dim3(8, 16), 256, 0, stream>>>(r_h, ht_h, h_h, proj, dbr);   // db1

  k4_pgemm<<<dim3(128, 4, 4), 256, 0, stream>>>(z_h, ht_h, r_h, h_h, proj, W1b, P);
  const float sc = 1.f / 64.f;
  // dW0/dW1/dW2 + dV0/dV1/dV2 in one 960-block launch
  k5_all<<<960, 256, 0, stream>>>(P, RsHpT, HpT, XT, r_h, ht_h, h_h, proj, dout, sc);
  k_dbP<<<dim3(512, 2), 256, 0, stream>>>(P, dbr);             // db0 (HV) + db2 (AV)
  k6a_sumsq<<<dim3(64, 9), 256, 0, stream>>>(dout, dbr, slots);
  k6b_write<<<dim3(64, 9), 256, 0, stream>>>(dbr, slots, dout);
}

// Round 9
// 2283.004 us; speedup vs baseline: 3.4247x; 1.0388x over previous
//
#include <hip/hip_runtime.h>
#include <hip/hip_bf16.h>

#define DI __device__ __forceinline__

typedef __bf16 bf16x8 __attribute__((ext_vector_type(8)));
typedef __bf16 bf16x4 __attribute__((ext_vector_type(4)));
typedef __bf16 bf16x2 __attribute__((ext_vector_type(2)));
typedef float  f32x4  __attribute__((ext_vector_type(4)));
typedef unsigned long long ull;

static constexpr int Bc = 64, Tc = 256, Ic = 128, Hc = 512, Oc = 64;
static constexpr int TBc = Tc * Bc;                 // 16384
static constexpr size_t THW = (size_t)TBc * Hc;     // 8388608 elems

// ---------- d_out offsets (floats) ----------
static constexpr size_t O_OUT = 0;
static constexpr size_t O_HT  = 4096;
static constexpr size_t O_DW0 = 36864;
static constexpr size_t O_DV0 = 823296;
static constexpr size_t O_DB0 = 1019904;
static constexpr size_t O_ERR = 1021440;

// ---------- ws offsets (bytes) ----------
static constexpr size_t W_SLOT = 1024;     // 9 f32
static constexpr size_t W_DB   = 2048;     // db_raw [3][512] f32 -> ends 8192
static constexpr size_t W_FLG  = 8192;     // barrier epoch flags: 64 slots x 128B -> ends 16384
static constexpr size_t W_ERRW = 16384;    // error [64][64] f32
static constexpr size_t W_PROJ = 32768;    // proj [6][64][512] f32 -> ends 819200
static constexpr size_t W_W1B  = 819200;   // W1 bf16 [512][512] -> ends 1343488
static constexpr size_t W_HX   = 1343488;  // h exchange fp32 [4][8192] (128 KB)
static constexpr size_t W_HRX  = 1474560;  // hr exchange fp32 [4][8192] -> ends 1605632
static constexpr size_t W_XT   = 1605632;  // x^T bf16 [128][TB] -> ends 5799936
static constexpr size_t W_HIST = 5799936;  // r,z,ht,h bf16 [TB][512] each -> ends 72908800
static constexpr size_t W_PB   = 72908800; // xV fp32 (100.6MB) / later P + HpT + RsHpT
static constexpr size_t W_NEED = W_PB + 100663296;   // 173572096

// =========================== helpers ===========================

DI void st32_agent(float* p, float v) {
  __hip_atomic_store((unsigned int*)p, __float_as_uint(v),
                     __ATOMIC_RELAXED, __HIP_MEMORY_SCOPE_AGENT);
}
DI ull ld64_agent(const void* p) {
  return __hip_atomic_load((ull*)p, __ATOMIC_RELAXED, __HIP_MEMORY_SCOPE_AGENT);
}

// Fence-free group barrier via distributed epoch flags (see R3/R6 notes).
DI void group_barrier(int* flags_g, int myslot, int bar, bool& dead) {
  __syncthreads();
  if (threadIdx.x == 0)
    __hip_atomic_store(&flags_g[myslot * 32], bar,
                       __ATOMIC_RELAXED, __HIP_MEMORY_SCOPE_AGENT);
  if (threadIdx.x < 64 && !dead) {
    const int l = threadIdx.x;
    int spins = 0;
    for (;;) {
      int v = bar;
      if (l < 16)
        v = __hip_atomic_load(&flags_g[l * 32],
                              __ATOMIC_RELAXED, __HIP_MEMORY_SCOPE_AGENT);
      if (__all(v >= bar)) break;
      __builtin_amdgcn_s_sleep(1);
      if (++spins > 4000000) { dead = true; break; }   // never hang the bench
    }
  }
  __syncthreads();
}

// hiddens[t-1] with python-negative-index quirk; k = t*64+b
DI float hprev_at(const __bf16* __restrict__ h_h, int k, int col) {
  int t = k >> 6;
  if (t == 1) return 0.f;
  int row = (t == 0) ? (16320 + (k & 63)) : (k - 128);
  return (float)h_h[(size_t)row * 512 + col];
}

// =========================== tiny kernels ===========================

__global__ void kzero(float* __restrict__ p, int n) {
  int i = blockIdx.x * 256 + threadIdx.x;
  if (i < n) p[i] = 0.f;
}
__global__ void ksent(float* p, float v) { p[0] = v; }

// =========================== K1: xV = x@V^T + bias via MFMA =================
// 2-way bf16 split both operands, 3-term Ootomo (error ~1e-4 on
// pre-activations, negligible vs the 2e-3 recurrence absmax).
__global__ __launch_bounds__(256)
void k1_xv(const float* __restrict__ x, const float* __restrict__ V1w,
           const float* __restrict__ V2w, const float* __restrict__ V3w,
           const float* __restrict__ V1b, const float* __restrict__ W2b,
           const float* __restrict__ W3b,
           float* __restrict__ xv1f, float* __restrict__ xv2f, float* __restrict__ xv3f)
{
  const int t = blockIdx.x, g = blockIdx.y;
  const float* Vg   = (g == 0) ? V1w : (g == 1) ? V2w : V3w;
  const float* bias = (g == 0) ? V1b : (g == 1) ? W2b : W3b;
  float* of = (g == 0) ? xv1f : (g == 1) ? xv2f : xv3f;
  __shared__ __align__(16) __bf16 xs0[64 * 36];
  __shared__ __align__(16) __bf16 xs1[64 * 36];
  __shared__ __align__(16) __bf16 vs0[64 * 36];
  __shared__ __align__(16) __bf16 vs1[64 * 36];
  const int tid = threadIdx.x, lane = tid & 63, wv = tid >> 6;
  const int q = lane >> 4, l15 = lane & 15;
  for (int cb = 0; cb < 8; ++cb) {
    f32x4 acc[4];
    #pragma unroll
    for (int mt = 0; mt < 4; ++mt) acc[mt] = (f32x4){0.f, 0.f, 0.f, 0.f};
    for (int kc = 0; kc < 4; ++kc) {
      __syncthreads();
      #pragma unroll
      for (int e = 0; e < 2; ++e) {
        int idx = tid + e * 256;           // 0..511
        int row = idx >> 3, k4 = (idx & 7) * 4;
        float4 v = *reinterpret_cast<const float4*>(&x[((size_t)row * 256 + t) * 128 + kc * 32 + k4]);
        float fv[4] = {v.x, v.y, v.z, v.w};
        bf16x4 a4, b4;
        #pragma unroll
        for (int j = 0; j < 4; ++j) {
          __bf16 a = (__bf16)fv[j];
          a4[j] = a; b4[j] = (__bf16)(fv[j] - (float)a);
        }
        *reinterpret_cast<bf16x4*>(&xs0[row * 36 + k4]) = a4;
        *reinterpret_cast<bf16x4*>(&xs1[row * 36 + k4]) = b4;
        float4 w = *reinterpret_cast<const float4*>(&Vg[(size_t)(cb * 64 + row) * 128 + kc * 32 + k4]);
        float fw[4] = {w.x, w.y, w.z, w.w};
        #pragma unroll
        for (int j = 0; j < 4; ++j) {
          __bf16 a = (__bf16)fw[j];
          a4[j] = a; b4[j] = (__bf16)(fw[j] - (float)a);
        }
        *reinterpret_cast<bf16x4*>(&vs0[row * 36 + k4]) = a4;
        *reinterpret_cast<bf16x4*>(&vs1[row * 36 + k4]) = b4;
      }
      __syncthreads();
      bf16x8 b0 = *reinterpret_cast<const bf16x8*>(&vs0[(wv * 16 + l15) * 36 + q * 8]);
      bf16x8 b1 = *reinterpret_cast<const bf16x8*>(&vs1[(wv * 16 + l15) * 36 + q * 8]);
      #pragma unroll
      for (int mt = 0; mt < 4; ++mt) {
        bf16x8 a0 = *reinterpret_cast<const bf16x8*>(&xs0[(mt * 16 + l15) * 36 + q * 8]);
        bf16x8 a1 = *reinterpret_cast<const bf16x8*>(&xs1[(mt * 16 + l15) * 36 + q * 8]);
        acc[mt] = __builtin_amdgcn_mfma_f32_16x16x32_bf16(a0, b0, acc[mt], 0, 0, 0);
        acc[mt] = __builtin_amdgcn_mfma_f32_16x16x32_bf16(a1, b0, acc[mt], 0, 0, 0);
        acc[mt] = __builtin_amdgcn_mfma_f32_16x16x32_bf16(a0, b1, acc[mt], 0, 0, 0);
      }
    }
    const int col = cb * 64 + wv * 16 + l15;
    const float bv = bias[col];
    #pragma unroll
    for (int mt = 0; mt < 4; ++mt)
      #pragma unroll
      for (int i = 0; i < 4; ++i) {
        int row = mt * 16 + q * 4 + i;
        of[((size_t)t * 64 + row) * 512 + col] = acc[mt][i] + bv;
      }
  }
}

// =========================== K2 mega-kernel =================================
// blocks 0..63: persistent GRU recurrence (R7's measured 1580us).
// blocks 64..319: e0_xt; 320..351: W1 cast; 352..415: zero grad accumulators.
__global__ __launch_bounds__(256, 1)
void k2_recur(const float* __restrict__ W1w, const float* __restrict__ W2w,
              const float* __restrict__ W3w,
              const float* __restrict__ xv1, const float* __restrict__ xv2,
              const float* __restrict__ xv3,
              __bf16* __restrict__ r_h, __bf16* __restrict__ z_h,
              __bf16* __restrict__ ht_h, __bf16* __restrict__ h_h,
              float* __restrict__ hx, float* __restrict__ hrx,
              int* __restrict__ flags, float* __restrict__ dout,
              const float* __restrict__ x, __bf16* __restrict__ XT,
              __bf16* __restrict__ W1b)
{
  __shared__ __align__(16) char smem[37376];
  const int tid = threadIdx.x;
  const int bid = blockIdx.x;

  if (bid >= 64) {
    if (bid < 320) {
      const int t = bid - 64;
      __bf16* xs = (__bf16*)smem;          // [64][132]
      #pragma unroll
      for (int e = 0; e < 8; ++e) {
        int idx = tid + e * 256;           // 0..2047
        int b = idx >> 5, c4 = (idx & 31) * 4;
        float4 v = *reinterpret_cast<const float4*>(&x[((size_t)b * 256 + t) * 128 + c4]);
        xs[b * 132 + c4 + 0] = (__bf16)v.x; xs[b * 132 + c4 + 1] = (__bf16)v.y;
        xs[b * 132 + c4 + 2] = (__bf16)v.z; xs[b * 132 + c4 + 3] = (__bf16)v.w;
      }
      __syncthreads();
      #pragma unroll
      for (int e = 0; e < 8; ++e) {
        int idx = tid + e * 256;
        int i = idx >> 4, b4 = (idx & 15) * 4;
        __bf16* d = &XT[(size_t)i * TBc + t * 64 + b4];
        d[0] = xs[(b4 + 0) * 132 + i];
        d[1] = xs[(b4 + 1) * 132 + i];
        d[2] = xs[(b4 + 2) * 132 + i];
        d[3] = xs[(b4 + 3) * 132 + i];
      }
    } else if (bid < 352) {
      for (int i = (bid - 320) * 256 + tid; i < 262144; i += 32 * 256)
        W1b[i] = (__bf16)W1w[i];
    } else {
      float* p = dout + O_DW0;
      for (int i = (bid - 352) * 256 + tid; i < 983040; i += 64 * 256)
        p[i] = 0.f;
    }
    return;
  }

  // ---------------- recurrence (identical to R7) ----------------
  const int g  = bid >> 4;
  const int cw = bid & 15;
  const int lane = tid & 63, wv = tid >> 6;
  const int kh = wv & 1;
  const int ct = wv >> 1;
  const int q  = lane >> 4;
  const int colc = cw * 32 + ct * 16 + (lane & 15);
  const bool owner = (kh == 0);

  __bf16* c0  = (__bf16*)smem;
  __bf16* c1  = (__bf16*)(smem + 16384);
  float*  pbuf = (float*)(smem + 32768);

  bf16x8 w1c[2][8], w2c[2][8], w3c[2][8];
  #pragma unroll
  for (int kk2 = 0; kk2 < 8; ++kk2) {
    const int kb = (kh * 8 + kk2) * 32 + q * 8;
    #pragma unroll
    for (int j = 0; j < 8; ++j) {
      float w = W1w[(size_t)colc * 512 + kb + j];
      __bf16 a = (__bf16)w;
      w1c[0][kk2][j] = a; w1c[1][kk2][j] = (__bf16)(w - (float)a);
      w = W2w[(size_t)colc * 512 + kb + j];
      a = (__bf16)w;
      w2c[0][kk2][j] = a; w2c[1][kk2][j] = (__bf16)(w - (float)a);
      w = W3w[(size_t)colc * 512 + kb + j];
      a = (__bf16)w;
      w3c[0][kk2][j] = a; w3c[1][kk2][j] = (__bf16)(w - (float)a);
    }
  }
  for (int i = tid; i < 8192; i += 256) {
    c0[i] = (__bf16)0.f; c1[i] = (__bf16)0.f;
  }
  __syncthreads();

  float hreg[4] = {0.f, 0.f, 0.f, 0.f};
  float* hx_g  = hx  + g * 8192;
  float* hrx_g = hrx + g * 8192;
  int* flags_g = flags + g * 16 * 32;
  const int fragbase = (colc >> 5) * 512 + (((colc >> 3) & 3) * 16 + q * 4) * 8 + (colc & 7);
  const int pb = (ct * 64 + lane) * 9;

  auto stage = [&](const float* __restrict__ srcf) {
    const ull* src = reinterpret_cast<const ull*>(srcf);
    ull u[16];
    #pragma unroll
    for (int j = 0; j < 16; ++j) u[j] = ld64_agent(src + j * 256 + tid);
    #pragma unroll
    for (int j = 0; j < 16; ++j) {
      float f0 = __uint_as_float((unsigned int)u[j]);
      float f1 = __uint_as_float((unsigned int)(u[j] >> 32));
      __bf16 a0 = (__bf16)f0; __bf16 b0 = (__bf16)(f0 - (float)a0);
      __bf16 a1 = (__bf16)f1; __bf16 b1 = (__bf16)(f1 - (float)a1);
      int o = (j * 256 + tid) * 2;
      bf16x2 v0; v0[0] = a0; v0[1] = a1;
      bf16x2 v1; v1[0] = b0; v1[1] = b1;
      *reinterpret_cast<bf16x2*>(&c0[o]) = v0;
      *reinterpret_cast<bf16x2*>(&c1[o]) = v1;
    }
  };

  bool dead = false;
  int bar = 0;
  #pragma unroll 1
  for (int t = 0; t < Tc; ++t) {
    const size_t rowb = ((size_t)t * 64 + g * 16 + q * 4) * 512 + colc;
    float xv1v[4], xv2v[4], xv3v[4];
    if (owner) {
      #pragma unroll
      for (int i = 0; i < 4; ++i) {
        size_t o = rowb + (size_t)i * 512;
        xv1v[i] = xv1[o]; xv2v[i] = xv2[o]; xv3v[i] = xv3[o];
      }
    }
    f32x4 a2 = {0.f,0.f,0.f,0.f}, a3 = {0.f,0.f,0.f,0.f};
    #pragma unroll
    for (int kk2 = 0; kk2 < 8; ++kk2) {
      const int idx = (kh * 8 + kk2) * 512 + lane * 8;
      bf16x8 h0 = *reinterpret_cast<const bf16x8*>(&c0[idx]);
      bf16x8 h1 = *reinterpret_cast<const bf16x8*>(&c1[idx]);
      a2 = __builtin_amdgcn_mfma_f32_16x16x32_bf16(h0, w2c[0][kk2], a2, 0, 0, 0);
      a2 = __builtin_amdgcn_mfma_f32_16x16x32_bf16(h1, w2c[0][kk2], a2, 0, 0, 0);
      a2 = __builtin_amdgcn_mfma_f32_16x16x32_bf16(h0, w2c[1][kk2], a2, 0, 0, 0);
      a3 = __builtin_amdgcn_mfma_f32_16x16x32_bf16(h0, w3c[0][kk2], a3, 0, 0, 0);
      a3 = __builtin_amdgcn_mfma_f32_16x16x32_bf16(h1, w3c[0][kk2], a3, 0, 0, 0);
      a3 = __builtin_amdgcn_mfma_f32_16x16x32_bf16(h0, w3c[1][kk2], a3, 0, 0, 0);
    }
    if (!owner) {
      #pragma unroll
      for (int i = 0; i < 4; ++i) { pbuf[pb + i] = a2[i]; pbuf[pb + 4 + i] = a3[i]; }
    }
    __syncthreads();
    float zz[4], rr4[4];
    if (owner) {
      #pragma unroll
      for (int i = 0; i < 4; ++i) {
        float s2 = a2[i] + pbuf[pb + i]     + xv2v[i];
        float s3 = a3[i] + pbuf[pb + 4 + i] + xv3v[i];
        zz[i]  = 1.f / (1.f + expf(-s2));
        rr4[i] = 1.f / (1.f + expf(-s3));
        st32_agent(&hrx_g[fragbase + i * 8], hreg[i] * rr4[i]);
      }
    }
    ++bar; group_barrier(flags_g, cw, bar, dead);
    if (owner) {
      #pragma unroll
      for (int i = 0; i < 4; ++i) {
        z_h[rowb + (size_t)i * 512] = (__bf16)zz[i];
        r_h[rowb + (size_t)i * 512] = (__bf16)rr4[i];
      }
    }
    stage(hrx_g);
    __syncthreads();
    f32x4 a1 = {0.f,0.f,0.f,0.f};
    #pragma unroll
    for (int kk2 = 0; kk2 < 8; ++kk2) {
      const int idx = (kh * 8 + kk2) * 512 + lane * 8;
      bf16x8 h0 = *reinterpret_cast<const bf16x8*>(&c0[idx]);
      bf16x8 h1 = *reinterpret_cast<const bf16x8*>(&c1[idx]);
      a1 = __builtin_amdgcn_mfma_f32_16x16x32_bf16(h0, w1c[0][kk2], a1, 0, 0, 0);
      a1 = __builtin_amdgcn_mfma_f32_16x16x32_bf16(h1, w1c[0][kk2], a1, 0, 0, 0);
      a1 = __builtin_amdgcn_mfma_f32_16x16x32_bf16(h0, w1c[1][kk2], a1, 0, 0, 0);
    }
    if (!owner) {
      #pragma unroll
      for (int i = 0; i < 4; ++i) pbuf[pb + i] = a1[i];
    }
    __syncthreads();
    float htv[4];
    if (owner) {
      #pragma unroll
      for (int i = 0; i < 4; ++i) {
        float pre = a1[i] + pbuf[pb + i] + xv1v[i];
        float ht = tanhf(pre);
        float hn = zz[i] * (hreg[i] - ht) + ht;
        htv[i] = ht;
        hreg[i] = hn;
        st32_agent(&hx_g[fragbase + i * 8], hn);
      }
    }
    ++bar; group_barrier(flags_g, cw, bar, dead);
    if (owner) {
      #pragma unroll
      for (int i = 0; i < 4; ++i) {
        ht_h[rowb + (size_t)i * 512] = (__bf16)htv[i];
        h_h[rowb + (size_t)i * 512]  = (__bf16)hreg[i];
      }
    }
    if (t + 1 < Tc) stage(hx_g);
    __syncthreads();
  }
  if (owner) {
    #pragma unroll
    for (int i = 0; i < 4; ++i) {
      int b = g * 16 + q * 4 + i;
      dout[O_HT + (size_t)b * 512 + colc] = hreg[i];
    }
  }
}

// =========================== K3M: e1t + k3a merged ==========================
// blocks 0..2047: e1t (HpT/RsHpT transposes); 2048..2063: softmax/error
// (4 batches/block, one wave each). Both depend only on k2 outputs.
// (db1/k_dbzg moved to k5m -- it reads proj, produced by k3b_proj AFTER this.)
__global__ __launch_bounds__(256)
void k3m(const __bf16* __restrict__ r_h, const __bf16* __restrict__ h_h,
         const float* __restrict__ Woutw, const float* __restrict__ Woutb,
         const int* __restrict__ y, float* __restrict__ dout,
         float* __restrict__ errw, __bf16* __restrict__ HpT,
         __bf16* __restrict__ RsHpT)
{
  __shared__ __align__(16) char smem[8704];
  const int bid = blockIdx.x, tid = threadIdx.x;
  if (bid < 2048) {
    // ---- e1t ----
    const int t = bid >> 3, hb = (bid & 7) * 64;
    __bf16* tr = (__bf16*)smem;     // [64][68]
    float hpv[16], rv[16];
    #pragma unroll
    for (int e = 0; e < 16; ++e) {
      int idx = tid + e * 256;
      int b = idx >> 6, hl = idx & 63;
      hpv[e] = hprev_at(h_h, t * 64 + b, hb + hl);
      rv[e]  = (float)r_h[((size_t)t * 64 + b) * 512 + hb + hl];
    }
    for (int rnd = 0; rnd < 2; ++rnd) {
      __syncthreads();
      #pragma unroll
      for (int e = 0; e < 16; ++e) {
        int idx = tid + e * 256;
        int b = idx >> 6, hl = idx & 63;
        tr[b * 68 + hl] = (__bf16)(rnd == 0 ? hpv[e] : rv[e] * hpv[e]);
      }
      __syncthreads();
      __bf16* dst = (rnd == 0) ? HpT : RsHpT;
      #pragma unroll
      for (int e = 0; e < 16; ++e) {
        int idx = tid + e * 256;
        int hl2 = idx >> 6, b2 = idx & 63;
        dst[(size_t)(hb + hl2) * TBc + t * 64 + b2] = tr[b2 * 68 + hl2];
      }
    }
  } else {
    // ---- k3a: softmax/error, one wave per batch row ----
    const int b = (bid - 2048) * 4 + (tid >> 6);
    const int o = tid & 63;
    const float* hrow = dout + O_HT + (size_t)b * 512;
    float sv = Woutb[o];
    for (int k = 0; k < 512; ++k) sv += hrow[k] * Woutw[(size_t)o * 512 + k];
    float mx = sv;
    for (int off = 32; off; off >>= 1) mx = fmaxf(mx, __shfl_xor(mx, off, 64));
    float e = expf(sv - mx);
    float sum = e;
    for (int off = 32; off; off >>= 1) sum += __shfl_xor(sum, off, 64);
    float outp = e / sum;
    float errv = outp - ((y[b] == o) ? 1.f : 0.f);
    dout[O_OUT + b * 64 + o] = outp;
    dout[O_ERR + b * 64 + o] = errv;
    errw[b * 64 + o] = errv;
  }
}

// =========================== K3b: 6 DFA projections ===========================
__global__ __launch_bounds__(256)
void k3b_proj(const float* __restrict__ err,
              const float* b0, const float* b1, const float* b2,
              const float* b3, const float* b4, const float* b5,
              float* __restrict__ proj)
{
  const int p = blockIdx.y;
  const int hb = blockIdx.x * 64;
  const float* BX = (p==0)?b0:(p==1)?b1:(p==2)?b2:(p==3)?b3:(p==4)?b4:b5;
  __shared__ float es[64 * 64];
  __shared__ float bs[64 * 65];
  for (int i = threadIdx.x; i < 4096; i += 256) es[i] = err[i];
  for (int i = threadIdx.x; i < 4096; i += 256) {
    int o = i >> 6, hh = i & 63;
    bs[o * 65 + hh] = BX[(size_t)o * 512 + hb + hh];
  }
  __syncthreads();
  for (int e = 0; e < 16; ++e) {
    int idx = threadIdx.x + e * 256;
    int b = idx >> 6, hh = idx & 63;
    float s = 0.f;
    for (int o = 0; o < 64; ++o) s += es[b * 64 + o] * bs[o * 65 + hh];
    proj[(size_t)p * 32768 + b * 512 + hb + hh] = s;
  }
}

// =========================== K4: plane-pair P GEMM ==========================
// pp=0 -> planes {0:AV,1:AW}; pp=1 -> planes {2:HV,3:HW}. Shared staging &
// epilogue loads -> ~half the memory traffic at identical MFMA count & math.
__global__ __launch_bounds__(256)
void k4_pgemm(const __bf16* __restrict__ z_h, const __bf16* __restrict__ ht_h,
              const __bf16* __restrict__ r_h, const __bf16* __restrict__ h_h,
              const float* __restrict__ proj, const __bf16* __restrict__ W1b,
              __bf16* __restrict__ P)
{
  const int pp = blockIdx.z;
  const int krow0 = blockIdx.x * 128;
  const int n0 = blockIdx.y * 128;
  const float* prA = proj + (size_t)(pp == 0 ? 5 : 1) * 32768;
  const float* prB = proj + (size_t)(pp == 0 ? 4 : 0) * 32768;
  const int tid = threadIdx.x, lane = tid & 63, wv = tid >> 6, q = lane >> 4;
  const int wm = (wv & 1) * 64, wn = (wv >> 1) * 64;
  __shared__ __align__(16) __bf16 Al0[128 * 40];
  __shared__ __align__(16) __bf16 Al1[128 * 40];
  __shared__ __align__(16) __bf16 Bl[128 * 40];
  f32x4 acc0[4][4] = {}, acc1[4][4] = {};
  for (int kt = 0; kt < 16; ++kt) {
    const int h0 = kt * 32;
    __syncthreads();
    #pragma unroll
    for (int e = 0; e < 4; ++e) {
      int idx = tid + e * 256;                 // 0..1023
      int row = idx >> 3, h4 = (idx & 7) * 4;
      int kg = krow0 + row;
      bf16x4 zz = *reinterpret_cast<const bf16x4*>(&z_h[(size_t)kg * 512 + h0 + h4]);
      float4 pva = *reinterpret_cast<const float4*>(&prA[(size_t)(kg & 63) * 512 + h0 + h4]);
      float4 pvb = *reinterpret_cast<const float4*>(&prB[(size_t)(kg & 63) * 512 + h0 + h4]);
      float pA[4] = {pva.x, pva.y, pva.z, pva.w};
      float pB[4] = {pvb.x, pvb.y, pvb.z, pvb.w};
      bf16x4 gv0, gv1;
      if (pp == 0) {
        bf16x4 tt = *reinterpret_cast<const bf16x4*>(&ht_h[(size_t)kg * 512 + h0 + h4]);
        #pragma unroll
        for (int j = 0; j < 4; ++j) {
          float sz = 1.f - (float)zz[j];
          float h = (float)tt[j];
          float f = sz * (1.f - h * h);
          gv0[j] = (__bf16)(pA[j] * f);
          gv1[j] = (__bf16)(pB[j] * f);
        }
      } else {
        #pragma unroll
        for (int j = 0; j < 4; ++j) {
          float sz = 1.f - (float)zz[j];
          gv0[j] = (__bf16)(pA[j] * sz);
          gv1[j] = (__bf16)(pB[j] * sz);
        }
      }
      *reinterpret_cast<bf16x4*>(&Al0[row * 40 + h4]) = gv0;
      *reinterpret_cast<bf16x4*>(&Al1[row * 40 + h4]) = gv1;
      bf16x4 wv4 = *reinterpret_cast<const bf16x4*>(&W1b[(size_t)(n0 + row) * 512 + h0 + h4]);
      *reinterpret_cast<bf16x4*>(&Bl[row * 40 + h4]) = wv4;
    }
    __syncthreads();
    bf16x8 af0[4], af1[4], bfv[4];
    #pragma unroll
    for (int mi = 0; mi < 4; ++mi) {
      af0[mi] = *reinterpret_cast<const bf16x8*>(&Al0[(wm + mi * 16 + (lane & 15)) * 40 + q * 8]);
      af1[mi] = *reinterpret_cast<const bf16x8*>(&Al1[(wm + mi * 16 + (lane & 15)) * 40 + q * 8]);
    }
    #pragma unroll
    for (int ni = 0; ni < 4; ++ni)
      bfv[ni] = *reinterpret_cast<const bf16x8*>(&Bl[(wn + ni * 16 + (lane & 15)) * 40 + q * 8]);
    #pragma unroll
    for (int mi = 0; mi < 4; ++mi)
      #pragma unroll
      for (int ni = 0; ni < 4; ++ni) {
        acc0[mi][ni] = __builtin_amdgcn_mfma_f32_16x16x32_bf16(af0[mi], bfv[ni], acc0[mi][ni], 0, 0, 0);
        acc1[mi][ni] = __builtin_amdgcn_mfma_f32_16x16x32_bf16(af1[mi], bfv[ni], acc1[mi][ni], 0, 0, 0);
      }
  }
  __bf16* Pp0 = P + (size_t)(2 * pp) * THW;
  __bf16* Pp1 = P + (size_t)(2 * pp + 1) * THW;
  #pragma unroll
  for (int mi = 0; mi < 4; ++mi) {
    const int kg = krow0 + wm + mi * 16 + q * 4;
    const int tt = kg >> 6;
    #pragma unroll
    for (int ni = 0; ni < 4; ++ni) {
      const int n = n0 + wn + ni * 16 + (lane & 15);
      union { __bf16 b[4]; uint2 u; } pk0, pk1;
      #pragma unroll
      for (int i = 0; i < 4; ++i) {
        float mul;
        if (pp == 0) {
          float r = (float)r_h[(size_t)(kg + i) * 512 + n];
          float hp = 0.f;
          if (tt != 1) {
            int kr = (tt == 0) ? (16320 + (kg & 63) + i) : (kg + i - 128);
            hp = (float)h_h[(size_t)kr * 512 + n];
          }
          mul = hp * r * (1.f - r);
        } else {
          float h = (float)ht_h[(size_t)(kg + i) * 512 + n];
          mul = 1.f - h * h;
        }
        pk0.b[i] = (__bf16)(acc0[mi][ni][i] * mul);
        pk1.b[i] = (__bf16)(acc1[mi][ni][i] * mul);
      }
      *reinterpret_cast<uint2*>(&Pp0[(size_t)n * TBc + kg]) = pk0.u;
      *reinterpret_cast<uint2*>(&Pp1[(size_t)n * TBc + kg]) = pk1.u;
    }
  }
}

// =========================== K5M: grad GEMMs + dbP + dbzg merged ============
// blocks 0..959: 6 TN grad GEMM jobs; 960..1983: k_dbP column sums (planes
// 2->db0, 0->db2); 1984..2111: k_dbzg db1 partials (reads proj[3], which
// k3b_proj produced before this launch). All inputs ready at launch.
__global__ __launch_bounds__(256)
void k5m(const __bf16* __restrict__ P, const __bf16* __restrict__ RsHpT,
         const __bf16* __restrict__ HpT, const __bf16* __restrict__ XT,
         const __bf16* __restrict__ r_h, const __bf16* __restrict__ ht_h,
         const __bf16* __restrict__ h_h, const float* __restrict__ proj,
         float* __restrict__ dout, float* __restrict__ db, float scale)
{
  __shared__ __align__(16) char smem[36864];
  const int bid = blockIdx.x, tid = threadIdx.x;
  if (bid >= 1984) {
    // ---- k_dbzg: db1 partials ----
    const int b2 = bid - 1984;
    const int hb = (b2 & 7) * 64;
    const int col = hb + (tid & 63);
    const int part = tid >> 6;
    const int kb = (b2 >> 3) * 1024;
    float sum = 0.f;
    for (int k = kb + part; k < kb + 1024; k += 4) {
      float hs = (float)ht_h[(size_t)k * 512 + col];
      float r  = (float)r_h[(size_t)k * 512 + col];
      float hp = hprev_at(h_h, k, col);
      float pv = proj[3 * 32768 + (size_t)(k & 63) * 512 + col];
      sum += (hp - hs) * r * (1.f - r) * pv;
    }
    float (*sred)[64] = (float(*)[64])smem;
    sred[part][tid & 63] = sum;
    __syncthreads();
    if (tid < 64)
      atomicAdd(&db[512 + hb + tid],
                (sred[0][tid] + sred[1][tid] + sred[2][tid] + sred[3][tid]) * (1.f / 64.f));
    return;
  }
  if (bid >= 960) {
    // ---- k_dbP ----
    const int idx = bid - 960;
    const size_t plane = ((idx >> 9) == 0) ? 2 : 0;
    const int dbo = ((idx >> 9) == 0) ? 0 : 1024;
    const int xrow = idx & 511;
    const __bf16* row = P + plane * THW + (size_t)xrow * TBc;
    float sv = 0.f;
    for (int i = tid; i < TBc; i += 256) sv += (float)row[i];
    for (int off = 32; off; off >>= 1) sv += __shfl_xor(sv, off, 64);
    float* red = (float*)smem;
    if ((tid & 63) == 0) red[tid >> 6] = sv;
    __syncthreads();
    if (tid == 0)
      atomicAdd(&db[dbo + xrow], (red[0] + red[1] + red[2] + red[3]) * (1.f / 64.f));
    return;
  }
  const __bf16* Ap; int amode; const __bf16* Bp; const float* projA;
  float* out; int N; int m0i, n0i, zi;
  if (bid < 768) {
    int job = bid >> 8, wb = bid & 255;
    m0i = wb & 3; n0i = (wb >> 2) & 3; zi = wb >> 4;
    N = 512;
    out = dout + O_DW0 + (size_t)job * 262144;
    if (job == 0)      { Ap = P + 3 * THW; amode = 0; Bp = RsHpT; projA = proj; }
    else if (job == 1) { Ap = nullptr;     amode = 1; Bp = HpT;   projA = proj + 2 * 32768; }
    else               { Ap = P + 1 * THW; amode = 0; Bp = HpT;   projA = proj; }
  } else {
    int b2 = bid - 768; int job = b2 >> 6, wb = b2 & 63;
    m0i = wb & 3; n0i = 0; zi = wb >> 2;
    N = 128;
    out = dout + O_DV0 + (size_t)job * 65536;
    if (job == 0)      { Ap = P + 2 * THW; amode = 0; Bp = XT; projA = proj; }
    else if (job == 1) { Ap = nullptr;     amode = 1; Bp = XT; projA = proj + 3 * 32768; }
    else               { Ap = P + 0 * THW; amode = 0; Bp = XT; projA = proj; }
  }
  const int m0 = m0i * 128;
  const int n0 = n0i * 128;
  const int klen = 1024;
  const int lane = tid & 63, wv = tid >> 6, q = lane >> 4;
  const int wm = (wv & 1) * 64, wn = (wv >> 1) * 64;
  __bf16* Al = (__bf16*)smem;                 // [128][72]
  __bf16* Bl = (__bf16*)(smem + 18432);       // [128][72]
  f32x4 acc[4][4] = {};
  const int iters = klen >> 6;
  for (int kt = 0; kt < iters; ++kt) {
    const int kk0 = zi * klen + kt * 64;
    __syncthreads();
    #pragma unroll
    for (int e = 0; e < 8; ++e) {
      int idx = tid + e * 256;              // 0..2047
      int row = idx >> 4, c4 = (idx & 15) * 4;
      bf16x4 bv = *reinterpret_cast<const bf16x4*>(&Bp[(size_t)(n0 + row) * TBc + kk0 + c4]);
      *reinterpret_cast<bf16x4*>(&Bl[row * 72 + c4]) = bv;
    }
    if (amode == 0) {
      #pragma unroll
      for (int e = 0; e < 8; ++e) {
        int idx = tid + e * 256;
        int row = idx >> 4, c4 = (idx & 15) * 4;
        bf16x4 av = *reinterpret_cast<const bf16x4*>(&Ap[(size_t)(m0 + row) * TBc + kk0 + c4]);
        *reinterpret_cast<bf16x4*>(&Al[row * 72 + c4]) = av;
      }
    } else {
      #pragma unroll
      for (int e = 0; e < 8; ++e) {
        int idx = tid + e * 256;
        int kk = idx >> 5;                  // 0..63 local k row
        int m4 = (idx & 31) * 4;
        int kg = kk0 + kk;
        int tt = kg >> 6;
        bf16x4 hs = *reinterpret_cast<const bf16x4*>(&ht_h[(size_t)kg * 512 + m0 + m4]);
        bf16x4 rv = *reinterpret_cast<const bf16x4*>(&r_h[(size_t)kg * 512 + m0 + m4]);
        float4 pv = *reinterpret_cast<const float4*>(&projA[(size_t)(kg & 63) * 512 + m0 + m4]);
        float pvv[4] = {pv.x, pv.y, pv.z, pv.w};
        float hpf[4] = {0.f, 0.f, 0.f, 0.f};
        if (tt != 1) {
          int kr = (tt == 0) ? (16320 + (kg & 63)) : (kg - 128);
          bf16x4 hp = *reinterpret_cast<const bf16x4*>(&h_h[(size_t)kr * 512 + m0 + m4]);
          #pragma unroll
          for (int j = 0; j < 4; ++j) hpf[j] = (float)hp[j];
        }
        #pragma unroll
        for (int j = 0; j < 4; ++j) {
          float r = (float)rv[j];
          float zg = (hpf[j] - (float)hs[j]) * r * (1.f - r) * pvv[j];
          Al[(m4 + j) * 72 + kk] = (__bf16)zg;
        }
      }
    }
    __syncthreads();
    #pragma unroll
    for (int ks = 0; ks < 2; ++ks) {
      bf16x8 af[4], bfv[4];
      #pragma unroll
      for (int mi = 0; mi < 4; ++mi)
        af[mi] = *reinterpret_cast<const bf16x8*>(&Al[(wm + mi * 16 + (lane & 15)) * 72 + ks * 32 + q * 8]);
      #pragma unroll
      for (int ni = 0; ni < 4; ++ni)
        bfv[ni] = *reinterpret_cast<const bf16x8*>(&Bl[(wn + ni * 16 + (lane & 15)) * 72 + ks * 32 + q * 8]);
      #pragma unroll
      for (int mi = 0; mi < 4; ++mi)
        #pragma unroll
        for (int ni = 0; ni < 4; ++ni)
          acc[mi][ni] = __builtin_amdgcn_mfma_f32_16x16x32_bf16(af[mi], bfv[ni], acc[mi][ni], 0, 0, 0);
    }
  }
  #pragma unroll
  for (int mi = 0; mi < 4; ++mi) {
    const int m = m0 + wm + mi * 16 + q * 4;
    #pragma unroll
    for (int ni = 0; ni < 4; ++ni) {
      const int n = n0 + wn + ni * 16 + (lane & 15);
      #pragma unroll
      for (int i = 0; i < 4; ++i)
        atomicAdd(&out[(size_t)(m + i) * N + n], acc[mi][ni][i] * scale);
    }
  }
}

// =========================== K6: norm + clip (grads live in d_out) ===========================
__global__ void k6a_sumsq(const float* __restrict__ dout, const float* __restrict__ db,
                          float* __restrict__ slots)
{
  const int yy = blockIdx.y;
  const float* src; int count;
  if (yy < 3)      { src = dout + O_DW0 + (size_t)yy * 262144; count = 262144; }
  else if (yy < 6) { src = dout + O_DV0 + (size_t)(yy - 3) * 65536; count = 65536; }
  else             { src = db + (size_t)(yy - 6) * 512; count = 512; }
  int start = blockIdx.x * 4096;
  if (start >= count) return;
  int end = min(start + 4096, count);
  float sp = 0.f;
  for (int i = start + threadIdx.x; i < end; i += 256) { float v = src[i]; sp += v * v; }
  for (int off = 32; off; off >>= 1) sp += __shfl_xor(sp, off, 64);
  __shared__ float red[4];
  if ((threadIdx.x & 63) == 0) red[threadIdx.x >> 6] = sp;
  __syncthreads();
  if (threadIdx.x == 0) atomicAdd(&slots[yy], red[0] + red[1] + red[2] + red[3]);
}

__global__ void k6b_write(const float* __restrict__ db,
                          const float* __restrict__ slots, float* __restrict__ dout)
{
  const int yy = blockIdx.y;
  const float* src; int count; size_t oo;
  if (yy < 3)      { oo = O_DW0 + (size_t)yy * 262144; src = dout + oo; count = 262144; }
  else if (yy < 6) { oo = O_DV0 + (size_t)(yy - 3) * 65536; src = dout + oo; count = 65536; }
  else             { oo = O_DB0 + (size_t)(yy - 6) * 512; src = db + (size_t)(yy - 6) * 512; count = 512; }
  int start = blockIdx.x * 4096;
  if (start >= count) return;
  int end = min(start + 4096, count);
  float inv = 1.f / sqrtf(slots[yy]);
  for (int i = start + threadIdx.x; i < end; i += 256) {
    float v = src[i] * inv;
    dout[oo + i] = fminf(fmaxf(v, -5.f), 5.f);
  }
}

// =========================== launch ===========================
extern "C" void kernel_launch(void* const* d_in, const int* in_sizes, int n_in,
                              void* d_out, int out_size, void* d_ws, size_t ws_size,
                              hipStream_t stream)
{
  const float* x     = (const float*)d_in[0];
  const int*   y     = (const int*)d_in[1];
  const float* W1w   = (const float*)d_in[2];
  const float* V1w   = (const float*)d_in[3];
  const float* V1b   = (const float*)d_in[4];
  const float* W2w   = (const float*)d_in[5];
  const float* W2b   = (const float*)d_in[6];
  const float* V2w   = (const float*)d_in[7];
  const float* W3w   = (const float*)d_in[8];
  const float* W3b   = (const float*)d_in[9];
  const float* V3w   = (const float*)d_in[10];
  const float* Woutw = (const float*)d_in[11];
  const float* Woutb = (const float*)d_in[12];
  const float* BW1   = (const float*)d_in[13];
  const float* BV1   = (const float*)d_in[14];
  const float* BW2   = (const float*)d_in[15];
  const float* BV2   = (const float*)d_in[16];
  const float* BW3   = (const float*)d_in[17];
  const float* BV3   = (const float*)d_in[18];
  float* dout = (float*)d_out;
  char* ws = (char*)d_ws;

  if (ws_size < W_NEED) { ksent<<<1, 1, 0, stream>>>(dout, (float)ws_size); return; }

  float*  slots = (float*)(ws + W_SLOT);
  float*  dbr   = (float*)(ws + W_DB);
  int*    flg   = (int*)(ws + W_FLG);
  float*  errw  = (float*)(ws + W_ERRW);
  float*  proj  = (float*)(ws + W_PROJ);
  __bf16* W1b   = (__bf16*)(ws + W_W1B);
  float*  hx    = (float*)(ws + W_HX);
  float*  hrx   = (float*)(ws + W_HRX);
  __bf16* XT    = (__bf16*)(ws + W_XT);
  __bf16* r_h   = (__bf16*)(ws + W_HIST);
  __bf16* z_h   = (__bf16*)(ws + W_HIST + 16777216);
  __bf16* ht_h  = (__bf16*)(ws + W_HIST + 33554432);
  __bf16* h_h   = (__bf16*)(ws + W_HIST + 50331648);
  char*   PB    = ws + W_PB;

  // xV fp32 (dead after k2) aliases P/HpT/RsHpT (live after k2)
  float* xv1 = (float*)PB;
  float* xv2 = (float*)(PB + 33554432);
  float* xv3 = (float*)(PB + 67108864);
  __bf16* P     = (__bf16*)PB;                     // 4 x [512][TB] bf16 = 67.1 MB
  __bf16* HpT   = (__bf16*)(PB + 67108864);
  __bf16* RsHpT = (__bf16*)(PB + 83886080);

  kzero<<<16, 256, 0, stream>>>((float*)ws, 4096);                  // slots+dbr+flags
  k1_xv<<<dim3(256, 3), 256, 0, stream>>>(x, V1w, V2w, V3w, V1b, W2b, W3b, xv1, xv2, xv3);
  // mega kernel: recurrence (blocks 0..63) + e0_xt (64..319) + W1 cast
  // (320..351) + grad-accumulator zero (352..415) on otherwise-idle CUs
  k2_recur<<<416, 256, 0, stream>>>(W1w, W2w, W3w, xv1, xv2, xv3,
                                    r_h, z_h, ht_h, h_h, hx, hrx, flg, dout,
                                    x, XT, W1b);
  // merged: e1t (0..2047) + k3a (2048..2063)
  k3m<<<2064, 256, 0, stream>>>(r_h, h_h, Woutw, Woutb, y, dout, errw, HpT, RsHpT);
  k3b_proj<<<dim3(8, 6), 256, 0, stream>>>(errw, BW1, BV1, BW2, BV2, BW3, BV3, proj);
  k4_pgemm<<<dim3(128, 4, 2), 256, 0, stream>>>(z_h, ht_h, r_h, h_h, proj, W1b, P);
  const float sc = 1.f / 64.f;
  // merged: dW/dV grad GEMMs (0..959) + k_dbP (960..1983) + k_dbzg (1984..2111)
  k5m<<<2112, 256, 0, stream>>>(P, RsHpT, HpT, XT, r_h, ht_h, h_h, proj, dout, dbr, sc);
  k6a_sumsq<<<dim3(64, 9), 256, 0, stream>>>(dout, dbr, slots);
  k6b_write<<<dim3(64, 9), 256, 0, stream>>>(dbr, slots, dout);
}